// Round 6
// baseline (413.388 us; speedup 1.0000x reference)
//
#include <hip/hip_runtime.h>
#include <cstdint>
#include <cstddef>

#define B_ 2
#define T_ 2048
#define D_ 2048
#define H_ 16
#define HD_ 128
#define EPS_ 1e-6f
#define QSCALE_ 0.08838834764831845f  // 1/sqrt(128)
#define KVSTRIDE_ (H_ * HD_)          // 2048 elems between consecutive t

typedef unsigned short u16;
typedef short s16x8 __attribute__((ext_vector_type(8)));
typedef float f32x4 __attribute__((ext_vector_type(4)));

__device__ __forceinline__ float bf2f(u16 h) {
  union { unsigned int u; float f; } v;
  v.u = ((unsigned int)h) << 16;
  return v.f;
}
__device__ __forceinline__ u16 f2bf(float f) {
  union { float f; unsigned int u; } v;
  v.f = f;
  unsigned int r = v.u + 0x7FFFu + ((v.u >> 16) & 1u);  // round-to-nearest-even
  return (u16)(r >> 16);
}

// async global->LDS, 16B per lane (LDS dest = wave-uniform base + lane*16)
__device__ __forceinline__ void gload16(const void* g, void* l) {
  __builtin_amdgcn_global_load_lds(
      (const __attribute__((address_space(1))) unsigned int*)g,
      (__attribute__((address_space(3))) unsigned int*)l, 16, 0, 0);
}

// ---------------- fused fp32 -> bf16 cast of all 5 tensors (1 launch) ----------------
// quad layout: [x: 2097152][Wq: 1048576][Wk: 1048576][Wv: 1048576][Wo: 1048576]
__global__ void cvt_all(const float* __restrict__ x, const float* __restrict__ Wq,
                        const float* __restrict__ Wk, const float* __restrict__ Wv,
                        const float* __restrict__ Wo, u16* __restrict__ xb,
                        u16* __restrict__ wqkb, u16* __restrict__ wvb, u16* __restrict__ wob) {
  const int XQ = 2097152, WQ = 1048576;
  int i = blockIdx.x * blockDim.x + threadIdx.x;
  const float* src;
  u16* dst;
  int off;
  if (i < XQ) { src = x; dst = xb; off = i; }
  else if (i < XQ + WQ) { src = Wq; dst = wqkb; off = i - XQ; }
  else if (i < XQ + 2 * WQ) { src = Wk; dst = wqkb + (size_t)WQ * 4; off = i - XQ - WQ; }
  else if (i < XQ + 3 * WQ) { src = Wv; dst = wvb; off = i - XQ - 2 * WQ; }
  else { src = Wo; dst = wob; off = i - XQ - 3 * WQ; }
  float4 v = ((const float4*)src)[off];
  ((ushort4*)dst)[off] = make_ushort4(f2bf(v.x), f2bf(v.y), f2bf(v.z), f2bf(v.w));
}

// ---------------- bf16 GEMM: C[M,N] = A[M,K] * Bm[N,K]^T (R7 counted-vmcnt) ----------------
// counted-vmcnt 2-tiles-ahead pipeline (T4):
//   prologue: STAGE(0,b0); STAGE(1,b1); vmcnt(8); bar
//   iter t:   ds_read frags(buf[t&1]); lgkmcnt(0); bar; STAGE(t+2 -> buf[t&1]);
//             32x MFMA; vmcnt(8) [t+1 landed, t+2 in flight]; bar
// vmcnt never drains to 0 in steady state; each tile ~2 compute phases cover.
// MODE: 0 = f32 out, 1 = bf16 out, 2 = QK-split (bf16; n0<2048 -> Cout,
// else Cout2 with col-2048; both stride 2048). n0 is block-uniform.
template <int MODE>
__global__ __launch_bounds__(256, 2) void gemm_btn(const u16* __restrict__ A,
                                                   const u16* __restrict__ Bm,
                                                   void* __restrict__ Cout,
                                                   void* __restrict__ Cout2,
                                                   int M, int N, int K) {
  __shared__ u16 As[2][2 * 128 * 32];
  __shared__ u16 Bs[2][2 * 128 * 32];
  const int tid = threadIdx.x;
  const int w = tid >> 6, lane = tid & 63, quad = lane >> 4, c = lane & 15;
  const int wm = w & 1, wn = w >> 1;
  const int m0 = blockIdx.y * 128, n0 = blockIdx.x * 128;
  const int NT = K >> 6;  // always 32 here (K=2048)

  f32x4 acc[4][4];
#pragma unroll
  for (int i = 0; i < 4; ++i)
#pragma unroll
    for (int j = 0; j < 4; ++j) acc[i][j] = (f32x4){0.f, 0.f, 0.f, 0.f};

  // 8 global_load_lds per thread => per-wave vmcnt +8 per STAGE.
  auto STAGE = [&](int t, int buf) {
    int k0 = t << 6;
#pragma unroll
    for (int i = 0; i < 4; ++i) {
      int chunk = (w * 4 + i) * 64 + lane;    // 0..1023
      int kc = chunk >> 9;                    // half-tile select (LDS-contiguous)
      int within = chunk & 511;
      int row = within >> 2, cc = within & 3; // 128 rows x 4 8-elem chunks
      gload16(A + (size_t)(m0 + row) * K + k0 + kc * 32 + cc * 8, (void*)(&As[buf][0] + chunk * 8));
      gload16(Bm + (size_t)(n0 + row) * K + k0 + kc * 32 + cc * 8, (void*)(&Bs[buf][0] + chunk * 8));
    }
  };

  STAGE(0, 0);
  STAGE(1, 1);
  asm volatile("s_waitcnt vmcnt(8)" ::: "memory");  // tile 0 landed (tile 1 in flight)
  __builtin_amdgcn_s_barrier();

  for (int t = 0; t < NT; ++t) {
    const int cur = t & 1;
    s16x8 af[4][2], bf[4][2];
#pragma unroll
    for (int kc = 0; kc < 2; ++kc) {
#pragma unroll
      for (int mi = 0; mi < 4; ++mi)
        af[mi][kc] = *(const s16x8*)(&As[cur][0] + kc * 4096 + (wm * 64 + mi * 16 + c) * 32 + quad * 8);
#pragma unroll
      for (int ni = 0; ni < 4; ++ni)
        bf[ni][kc] = *(const s16x8*)(&Bs[cur][0] + kc * 4096 + (wn * 64 + ni * 16 + c) * 32 + quad * 8);
    }
    // all reads of buf[cur] retired before any wave's DMA may overwrite it
    asm volatile("s_waitcnt lgkmcnt(0)" ::: "memory");
    __builtin_amdgcn_s_barrier();
    if (t + 2 < NT) STAGE(t + 2, cur);  // 2 tiles ahead into the freed buffer

#pragma unroll
    for (int kc = 0; kc < 2; ++kc)
#pragma unroll
      for (int mi = 0; mi < 4; ++mi)
#pragma unroll
        for (int ni = 0; ni < 4; ++ni)
          acc[mi][ni] = __builtin_amdgcn_mfma_f32_16x16x32_bf16(af[mi][kc], bf[ni][kc], acc[mi][ni], 0, 0, 0);

    if (t + 1 < NT) {
      if (t + 2 < NT)
        asm volatile("s_waitcnt vmcnt(8)" ::: "memory");  // tile t+1 landed, t+2 in flight
      else
        asm volatile("s_waitcnt vmcnt(0)" ::: "memory");  // last refill: full drain
      __builtin_amdgcn_s_barrier();
    }
  }

  // epilogue (no outstanding DMA: drained at t=NT-2)
  u16* dst16 = (u16*)Cout;
  int coloff = 0, nstride = N;
  if (MODE == 2) {
    nstride = 2048;
    if (n0 >= 2048) { dst16 = (u16*)Cout2; coloff = -2048; }
  }
#pragma unroll
  for (int mi = 0; mi < 4; ++mi)
#pragma unroll
    for (int ni = 0; ni < 4; ++ni)
#pragma unroll
      for (int r = 0; r < 4; ++r) {
        int row = m0 + wm * 64 + mi * 16 + quad * 4 + r;
        int col = n0 + wn * 64 + ni * 16 + c + coloff;
        float v = acc[mi][ni][r];
        if (MODE == 0)
          ((float*)Cout)[(size_t)row * N + col] = v;
        else
          dst16[(size_t)row * nstride + col] = f2bf(v);
      }
}

// ---------------- fused RMSNorm + interleaved RoPE for q AND k (1 launch) ----------------
__global__ void rmsnorm_rope2(u16* __restrict__ qx, u16* __restrict__ kx,
                              const float* __restrict__ qw, const float* __restrict__ kw) {
  const int tid = threadIdx.x;
  const int w = tid >> 6, lane = tid & 63;
  const int bid = blockIdx.x;
  const bool isq = bid < 16384;
  u16* x = isq ? qx : kx;
  const float* nw = isq ? qw : kw;
  const float outscale = isq ? QSCALE_ : 1.0f;
  const int vec = (bid & 16383) * 4 + w;  // (b*T + t)*H + h
  const int t = (vec >> 4) & (T_ - 1);    // /H % T
  u16* base = x + (size_t)vec * HD_;
  unsigned int pk = *(const unsigned int*)(base + lane * 2);
  float e = bf2f((u16)(pk & 0xFFFFu));
  float o = bf2f((u16)(pk >> 16));
  float ss = e * e + o * o;
#pragma unroll
  for (int off = 1; off < 64; off <<= 1) ss += __shfl_xor(ss, off, 64);
  float rn = rsqrtf(ss * (1.0f / HD_) + EPS_);
  float we = nw[lane * 2], wo = nw[lane * 2 + 1];
  e = e * rn * we;
  o = o * rn * wo;
  float freq = expf(-(float)lane * (9.210340371976184f / 64.0f));  // 10000^(-lane/64)
  float ang = (float)t * freq;
  float sn, cs;
  sincosf(ang, &sn, &cs);
  float re = (e * cs - o * sn) * outscale;
  float ro = (e * sn + o * cs) * outscale;
  *(unsigned int*)(base + lane * 2) = ((unsigned int)f2bf(ro) << 16) | (unsigned int)f2bf(re);
}

// ---------------- causal flash attention, Br=128, Bc=64, bf16 MFMA ----------------
// R8: Q tile 128 rows/block (was 64). Each wave owns 32 Q rows = 2 row-groups
// (mi=0,1). K/V staging, K/V fragment ds_reads, barriers and DMA issue are
// per-TILE costs that now serve 2x the MFMA work: LDS-read traffic per FLOP
// halves, block-iters 16896 -> 8704. K/V frags are read once and feed both mi
// (reuse in regs). LDS = 32K Ks + 32K Vts + 16K Ps = 80 KiB -> 2 blocks/CU
// (exactly the 160 KiB pool). Causal: per-wave jmax_w (waves 0-1 skip the last
// tile's compute); elementwise mask only at j == jmax_w (for j < jmax_w all
// cols < all rows, proven: jmax_w*64 <= wr0+31 and wr0 % 32 == 0).
// Kept from R5-R7: XOR slot-swizzle, DMA staging w/ inverse-swizzled source,
// wave-private Ps (no extra barrier), 2-phase prefetch, deferred l-reduction.
__global__ __launch_bounds__(256, 2) void attn_fwd(const u16* __restrict__ Q,
                                                   const u16* __restrict__ Kg,
                                                   const u16* __restrict__ Vt,
                                                   u16* __restrict__ O) {
  __shared__ u16 Ks[2][64 * 128];   // K rows (s-major, d contig), slot-swizzled
  __shared__ u16 Vts[2][128 * 64];  // V^T rows (d-major, s contig), slot-swizzled
  __shared__ u16 Ps[128 * 64];      // P round-trip (wave-private rows), slot-swizzled
  const int tid = threadIdx.x;
  const int w = tid >> 6, lane = tid & 63, quad = lane >> 4, c = lane & 15;
  const int c7 = (c & 7) * 8;       // read-side XOR (row%8 == c%8 for all frag reads)
  const int bid = blockIdx.x;
  const int qtile = 15 - (bid >> 5);  // heavy blocks dispatch first
  const int h = bid & 15;
  const int b = (bid >> 4) & 1;
  const int q0 = qtile * 128;
  const int wr0 = q0 + w * 32;              // this wave's first Q row
  const int jmax_blk = 2 * qtile + 1;       // last K tile any wave needs
  const int jmax_w = (wr0 + 31) >> 6;       // last K tile THIS wave needs

  // Q fragments in registers: rows wr0 + mi*16 + c (A-layout)
  s16x8 qf[2][4];
#pragma unroll
  for (int mi = 0; mi < 2; ++mi) {
    const u16* qbase = Q + ((size_t)(b * T_ + wr0 + mi * 16 + c) * H_ + h) * HD_;
#pragma unroll
    for (int kk = 0; kk < 4; ++kk) qf[mi][kk] = *(const s16x8*)(qbase + kk * 32 + quad * 8);
  }

  f32x4 of[2][8];
#pragma unroll
  for (int mi = 0; mi < 2; ++mi)
#pragma unroll
    for (int i = 0; i < 8; ++i) of[mi][i] = (f32x4){0.f, 0.f, 0.f, 0.f};
  float m_i[2][4], lp[2][4];
#pragma unroll
  for (int mi = 0; mi < 2; ++mi)
#pragma unroll
    for (int r = 0; r < 4; ++r) { m_i[mi][r] = -1e30f; lp[mi][r] = 0.f; }

  const u16* kbase = Kg + ((size_t)b * T_ * H_ + h) * HD_;
  const u16* vtbase = Vt + (size_t)(h * HD_) * (B_ * T_) + (size_t)b * T_;

  auto STAGE = [&](int j, int buf) {
    const u16* krow = kbase + (size_t)(j * 64) * KVSTRIDE_;
    const u16* vrow = vtbase + j * 64;
#pragma unroll
    for (int i = 0; i < 4; ++i) {
      int chunk = i * 256 + tid;  // 0..1023
      int krowi = chunk >> 4, kslot = (chunk & 15) ^ (krowi & 7);
      gload16(krow + (size_t)krowi * KVSTRIDE_ + kslot * 8, (void*)(&Ks[buf][0] + chunk * 8));
      int vrowi = chunk >> 3, vslot = (chunk & 7) ^ (vrowi & 7);
      gload16(vrow + (size_t)vrowi * (B_ * T_) + vslot * 8, (void*)(&Vts[buf][0] + chunk * 8));
    }
  };

  STAGE(0, 0);
  __syncthreads();  // vmcnt(0) drain -> tile 0 ready
  int cur = 0;

  for (int j = 0; j <= jmax_blk; ++j) {
    if (j < jmax_blk) STAGE(j + 1, cur ^ 1);

    if (j <= jmax_w) {  // wave-uniform: waves 0-1 skip the block's last tile
      // S = Q K^T : 16 Ks frag reads feed 32 MFMA (both mi)
      f32x4 sf[2][4];
#pragma unroll
      for (int mi = 0; mi < 2; ++mi)
#pragma unroll
        for (int ni = 0; ni < 4; ++ni) sf[mi][ni] = (f32x4){0.f, 0.f, 0.f, 0.f};
#pragma unroll
      for (int ni = 0; ni < 4; ++ni)
#pragma unroll
        for (int kk = 0; kk < 4; ++kk) {
          s16x8 bfr = *(const s16x8*)(&Ks[cur][(ni * 16 + c) * 128 + ((kk * 32 + quad * 8) ^ c7)]);
#pragma unroll
          for (int mi = 0; mi < 2; ++mi)
            sf[mi][ni] = __builtin_amdgcn_mfma_f32_16x16x32_bf16(qf[mi][kk], bfr, sf[mi][ni], 0, 0, 0);
        }
      // causal mask: only possible at this wave's diagonal tile
      if (j == jmax_w) {
#pragma unroll
        for (int mi = 0; mi < 2; ++mi)
#pragma unroll
          for (int ni = 0; ni < 4; ++ni)
#pragma unroll
            for (int r = 0; r < 4; ++r) {
              int rowg = wr0 + mi * 16 + quad * 4 + r;
              int colg = j * 64 + ni * 16 + c;
              if (colg > rowg) sf[mi][ni][r] = -1e30f;
            }
      }
      // online softmax per row-group (rows live across the 16 c-lanes)
#pragma unroll
      for (int mi = 0; mi < 2; ++mi) {
        float mc[4];
#pragma unroll
        for (int r = 0; r < 4; ++r)
          mc[r] = fmaxf(fmaxf(sf[mi][0][r], sf[mi][1][r]), fmaxf(sf[mi][2][r], sf[mi][3][r]));
#pragma unroll
        for (int off = 1; off < 16; off <<= 1)
#pragma unroll
          for (int r = 0; r < 4; ++r) mc[r] = fmaxf(mc[r], __shfl_xor(mc[r], off, 64));
#pragma unroll
        for (int r = 0; r < 4; ++r) {
          float mnew = fmaxf(m_i[mi][r], mc[r]);
          float alpha = __expf(m_i[mi][r] - mnew);
          m_i[mi][r] = mnew;
          lp[mi][r] *= alpha;
#pragma unroll
          for (int ot = 0; ot < 8; ++ot) of[mi][ot][r] *= alpha;
        }
#pragma unroll
        for (int ni = 0; ni < 4; ++ni)
#pragma unroll
          for (int r = 0; r < 4; ++r) {
            float p = __expf(sf[mi][ni][r] - m_i[mi][r]);
            sf[mi][ni][r] = p;
            lp[mi][r] += p;
          }
        // write P (local rows w*32+mi*16+quad*4+r), swizzled; wave-private -> no barrier
#pragma unroll
        for (int ni = 0; ni < 4; ++ni)
#pragma unroll
          for (int r = 0; r < 4; ++r) {
            int row = w * 32 + mi * 16 + quad * 4 + r;
            Ps[row * 64 + ((ni * 16 + c) ^ ((row & 7) * 8))] = f2bf(sf[mi][ni][r]);
          }
      }
      // O += P V : 16 Vts frag reads feed 32 MFMA (both mi)
      s16x8 pa[2][2];
#pragma unroll
      for (int mi = 0; mi < 2; ++mi) {
        int prow = w * 32 + mi * 16 + c;
        pa[mi][0] = *(const s16x8*)(&Ps[prow * 64 + ((quad * 8) ^ c7)]);
        pa[mi][1] = *(const s16x8*)(&Ps[prow * 64 + ((32 + quad * 8) ^ c7)]);
      }
#pragma unroll
      for (int ot = 0; ot < 8; ++ot)
#pragma unroll
        for (int kk = 0; kk < 2; ++kk) {
          s16x8 vfr = *(const s16x8*)(&Vts[cur][(ot * 16 + c) * 64 + ((kk * 32 + quad * 8) ^ c7)]);
#pragma unroll
          for (int mi = 0; mi < 2; ++mi)
            of[mi][ot] = __builtin_amdgcn_mfma_f32_16x16x32_bf16(pa[mi][kk], vfr, of[mi][ot], 0, 0, 0);
        }
    }

    __syncthreads();  // drains prefetch (covered by compute) + fences buf reuse
    cur ^= 1;
  }

  // epilogue: reduce l partials, O /= l, store bf16 ctx (flat (B,T,H,HD))
#pragma unroll
  for (int off = 1; off < 16; off <<= 1)
#pragma unroll
    for (int mi = 0; mi < 2; ++mi)
#pragma unroll
      for (int r = 0; r < 4; ++r) lp[mi][r] += __shfl_xor(lp[mi][r], off, 64);
#pragma unroll
  for (int mi = 0; mi < 2; ++mi) {
    float inv[4];
#pragma unroll
    for (int r = 0; r < 4; ++r) inv[r] = 1.0f / lp[mi][r];
    u16* obase = O + ((size_t)(b * T_ + wr0 + mi * 16) * H_ + h) * HD_;
#pragma unroll
    for (int ot = 0; ot < 8; ++ot)
#pragma unroll
      for (int r = 0; r < 4; ++r)
        obase[(size_t)(quad * 4 + r) * KVSTRIDE_ + ot * 16 + c] = f2bf(of[mi][ot][r] * inv[r]);
  }
}

// ---------------- launch ----------------
extern "C" void kernel_launch(void* const* d_in, const int* in_sizes, int n_in,
                              void* d_out, int out_size, void* d_ws, size_t ws_size,
                              hipStream_t stream) {
  const float* x = (const float*)d_in[0];
  const float* Wq = (const float*)d_in[1];
  const float* Wk = (const float*)d_in[2];
  const float* Wv = (const float*)d_in[3];
  const float* Wo = (const float*)d_in[4];
  const float* qw = (const float*)d_in[5];
  const float* kw = (const float*)d_in[6];
  float* out = (float*)d_out;

  const size_t xE = (size_t)B_ * T_ * D_;   // 8388608
  const size_t wE = (size_t)D_ * H_ * HD_;  // 4194304
  const size_t need = xE * 2 * 5 + wE * 2 * 4;  // ~112 MB
  if (ws_size < need) return;

  char* ws = (char*)d_ws;
  u16* xb = (u16*)ws;    ws += xE * 2;
  u16* wqkb = (u16*)ws;  ws += wE * 2 * 2;  // Wq || Wk adjacent -> one fused GEMM
  u16* wvb = (u16*)ws;   ws += wE * 2;
  u16* wob = (u16*)ws;   ws += wE * 2;
  u16* qb = (u16*)ws;    ws += xE * 2;
  u16* kb = (u16*)ws;    ws += xE * 2;
  u16* vtb = (u16*)ws;   ws += xE * 2;   // V^T: [H*HD][B*T]
  u16* ctxb = (u16*)ws;  ws += xE * 2;

  // single fused cast launch (x, Wq, Wk, Wv, Wo)
  cvt_all<<<24576, 256, 0, stream>>>(x, Wq, Wk, Wv, Wo, xb, wqkb, wvb, wob);

  // fused QK GEMM: C[4096 tok][4096] = xb * (Wq||Wk)^T, split into qb/kb
  dim3 gqk(32, 32);
  gemm_btn<2><<<gqk, 256, 0, stream>>>(xb, wqkb, qb, kb, 4096, 4096, 2048);
  // V^T = Wv * x^T : M=2048 (o), N=4096 (tokens)
  dim3 ggv(32, 16);
  gemm_btn<1><<<ggv, 256, 0, stream>>>(wvb, xb, vtb, nullptr, 2048, 4096, 2048);

  // fused q+k rmsnorm/rope (1 launch)
  rmsnorm_rope2<<<32768, 256, 0, stream>>>(qb, kb, qw, kw);

  attn_fwd<<<B_ * H_ * (T_ / 128), 256, 0, stream>>>(qb, kb, vtb, ctxb);

  dim3 gg(16, 32);
  gemm_btn<0><<<gg, 256, 0, stream>>>(ctxb, wob, out, nullptr, 4096, 2048, 2048);
}

// Round 7
// 389.157 us; speedup vs baseline: 1.0623x; 1.0623x over previous
//
#include <hip/hip_runtime.h>
#include <cstdint>
#include <cstddef>

#define B_ 2
#define T_ 2048
#define D_ 2048
#define H_ 16
#define HD_ 128
#define EPS_ 1e-6f
#define QSCALE_ 0.08838834764831845f  // 1/sqrt(128)
#define KVSTRIDE_ (H_ * HD_)          // 2048 elems between consecutive t

typedef unsigned short u16;
typedef short s16x8 __attribute__((ext_vector_type(8)));
typedef float f32x4 __attribute__((ext_vector_type(4)));

__device__ __forceinline__ float bf2f(u16 h) {
  union { unsigned int u; float f; } v;
  v.u = ((unsigned int)h) << 16;
  return v.f;
}
__device__ __forceinline__ u16 f2bf(float f) {
  union { float f; unsigned int u; } v;
  v.f = f;
  unsigned int r = v.u + 0x7FFFu + ((v.u >> 16) & 1u);  // round-to-nearest-even
  return (u16)(r >> 16);
}

// async global->LDS, 16B per lane (LDS dest = wave-uniform base + lane*16)
__device__ __forceinline__ void gload16(const void* g, void* l) {
  __builtin_amdgcn_global_load_lds(
      (const __attribute__((address_space(1))) unsigned int*)g,
      (__attribute__((address_space(3))) unsigned int*)l, 16, 0, 0);
}

// ---------------- fused fp32 -> bf16 cast of all 5 tensors (1 launch) ----------------
// quad layout: [x: 2097152][Wq: 1048576][Wk: 1048576][Wv: 1048576][Wo: 1048576]
__global__ void cvt_all(const float* __restrict__ x, const float* __restrict__ Wq,
                        const float* __restrict__ Wk, const float* __restrict__ Wv,
                        const float* __restrict__ Wo, u16* __restrict__ xb,
                        u16* __restrict__ wqkb, u16* __restrict__ wvb, u16* __restrict__ wob) {
  const int XQ = 2097152, WQ = 1048576;
  int i = blockIdx.x * blockDim.x + threadIdx.x;
  const float* src;
  u16* dst;
  int off;
  if (i < XQ) { src = x; dst = xb; off = i; }
  else if (i < XQ + WQ) { src = Wq; dst = wqkb; off = i - XQ; }
  else if (i < XQ + 2 * WQ) { src = Wk; dst = wqkb + (size_t)WQ * 4; off = i - XQ - WQ; }
  else if (i < XQ + 3 * WQ) { src = Wv; dst = wvb; off = i - XQ - 2 * WQ; }
  else { src = Wo; dst = wob; off = i - XQ - 3 * WQ; }
  float4 v = ((const float4*)src)[off];
  ((ushort4*)dst)[off] = make_ushort4(f2bf(v.x), f2bf(v.y), f2bf(v.z), f2bf(v.w));
}

// ---------------- bf16 GEMM: C[M,N] = A[M,K] * Bm[N,K]^T (R7 counted-vmcnt) ----------------
// counted-vmcnt 2-tiles-ahead pipeline (T4):
//   prologue: STAGE(0,b0); STAGE(1,b1); vmcnt(8); bar
//   iter t:   ds_read frags(buf[t&1]); lgkmcnt(0); bar; STAGE(t+2 -> buf[t&1]);
//             32x MFMA; vmcnt(8) [t+1 landed, t+2 in flight]; bar
// vmcnt never drains to 0 in steady state; each tile ~2 compute phases cover.
// MODE: 0 = f32 out, 1 = bf16 out, 2 = QK-split (bf16; n0<2048 -> Cout,
// else Cout2 with col-2048; both stride 2048). n0 is block-uniform.
template <int MODE>
__global__ __launch_bounds__(256, 2) void gemm_btn(const u16* __restrict__ A,
                                                   const u16* __restrict__ Bm,
                                                   void* __restrict__ Cout,
                                                   void* __restrict__ Cout2,
                                                   int M, int N, int K) {
  __shared__ u16 As[2][2 * 128 * 32];
  __shared__ u16 Bs[2][2 * 128 * 32];
  const int tid = threadIdx.x;
  const int w = tid >> 6, lane = tid & 63, quad = lane >> 4, c = lane & 15;
  const int wm = w & 1, wn = w >> 1;
  const int m0 = blockIdx.y * 128, n0 = blockIdx.x * 128;
  const int NT = K >> 6;  // always 32 here (K=2048)

  f32x4 acc[4][4];
#pragma unroll
  for (int i = 0; i < 4; ++i)
#pragma unroll
    for (int j = 0; j < 4; ++j) acc[i][j] = (f32x4){0.f, 0.f, 0.f, 0.f};

  // 8 global_load_lds per thread => per-wave vmcnt +8 per STAGE.
  auto STAGE = [&](int t, int buf) {
    int k0 = t << 6;
#pragma unroll
    for (int i = 0; i < 4; ++i) {
      int chunk = (w * 4 + i) * 64 + lane;    // 0..1023
      int kc = chunk >> 9;                    // half-tile select (LDS-contiguous)
      int within = chunk & 511;
      int row = within >> 2, cc = within & 3; // 128 rows x 4 8-elem chunks
      gload16(A + (size_t)(m0 + row) * K + k0 + kc * 32 + cc * 8, (void*)(&As[buf][0] + chunk * 8));
      gload16(Bm + (size_t)(n0 + row) * K + k0 + kc * 32 + cc * 8, (void*)(&Bs[buf][0] + chunk * 8));
    }
  };

  STAGE(0, 0);
  STAGE(1, 1);
  asm volatile("s_waitcnt vmcnt(8)" ::: "memory");  // tile 0 landed (tile 1 in flight)
  __builtin_amdgcn_s_barrier();

  for (int t = 0; t < NT; ++t) {
    const int cur = t & 1;
    s16x8 af[4][2], bf[4][2];
#pragma unroll
    for (int kc = 0; kc < 2; ++kc) {
#pragma unroll
      for (int mi = 0; mi < 4; ++mi)
        af[mi][kc] = *(const s16x8*)(&As[cur][0] + kc * 4096 + (wm * 64 + mi * 16 + c) * 32 + quad * 8);
#pragma unroll
      for (int ni = 0; ni < 4; ++ni)
        bf[ni][kc] = *(const s16x8*)(&Bs[cur][0] + kc * 4096 + (wn * 64 + ni * 16 + c) * 32 + quad * 8);
    }
    // all reads of buf[cur] retired before any wave's DMA may overwrite it
    asm volatile("s_waitcnt lgkmcnt(0)" ::: "memory");
    __builtin_amdgcn_s_barrier();
    if (t + 2 < NT) STAGE(t + 2, cur);  // 2 tiles ahead into the freed buffer

#pragma unroll
    for (int kc = 0; kc < 2; ++kc)
#pragma unroll
      for (int mi = 0; mi < 4; ++mi)
#pragma unroll
        for (int ni = 0; ni < 4; ++ni)
          acc[mi][ni] = __builtin_amdgcn_mfma_f32_16x16x32_bf16(af[mi][kc], bf[ni][kc], acc[mi][ni], 0, 0, 0);

    if (t + 1 < NT) {
      if (t + 2 < NT)
        asm volatile("s_waitcnt vmcnt(8)" ::: "memory");  // tile t+1 landed, t+2 in flight
      else
        asm volatile("s_waitcnt vmcnt(0)" ::: "memory");  // last refill: full drain
      __builtin_amdgcn_s_barrier();
    }
  }

  // epilogue (no outstanding DMA: drained at t=NT-2)
  u16* dst16 = (u16*)Cout;
  int coloff = 0, nstride = N;
  if (MODE == 2) {
    nstride = 2048;
    if (n0 >= 2048) { dst16 = (u16*)Cout2; coloff = -2048; }
  }
#pragma unroll
  for (int mi = 0; mi < 4; ++mi)
#pragma unroll
    for (int ni = 0; ni < 4; ++ni)
#pragma unroll
      for (int r = 0; r < 4; ++r) {
        int row = m0 + wm * 64 + mi * 16 + quad * 4 + r;
        int col = n0 + wn * 64 + ni * 16 + c + coloff;
        float v = acc[mi][ni][r];
        if (MODE == 0)
          ((float*)Cout)[(size_t)row * N + col] = v;
        else
          dst16[(size_t)row * nstride + col] = f2bf(v);
      }
}

// ---------------- fused RMSNorm + interleaved RoPE for q AND k (1 launch) ----------------
__global__ void rmsnorm_rope2(u16* __restrict__ qx, u16* __restrict__ kx,
                              const float* __restrict__ qw, const float* __restrict__ kw) {
  const int tid = threadIdx.x;
  const int w = tid >> 6, lane = tid & 63;
  const int bid = blockIdx.x;
  const bool isq = bid < 16384;
  u16* x = isq ? qx : kx;
  const float* nw = isq ? qw : kw;
  const float outscale = isq ? QSCALE_ : 1.0f;
  const int vec = (bid & 16383) * 4 + w;  // (b*T + t)*H + h
  const int t = (vec >> 4) & (T_ - 1);    // /H % T
  u16* base = x + (size_t)vec * HD_;
  unsigned int pk = *(const unsigned int*)(base + lane * 2);
  float e = bf2f((u16)(pk & 0xFFFFu));
  float o = bf2f((u16)(pk >> 16));
  float ss = e * e + o * o;
#pragma unroll
  for (int off = 1; off < 64; off <<= 1) ss += __shfl_xor(ss, off, 64);
  float rn = rsqrtf(ss * (1.0f / HD_) + EPS_);
  float we = nw[lane * 2], wo = nw[lane * 2 + 1];
  e = e * rn * we;
  o = o * rn * wo;
  float freq = expf(-(float)lane * (9.210340371976184f / 64.0f));  // 10000^(-lane/64)
  float ang = (float)t * freq;
  float sn, cs;
  sincosf(ang, &sn, &cs);
  float re = (e * cs - o * sn) * outscale;
  float ro = (e * sn + o * cs) * outscale;
  *(unsigned int*)(base + lane * 2) = ((unsigned int)f2bf(ro) << 16) | (unsigned int)f2bf(re);
}

// ---------------- causal flash attention, Br=128, Bc=64, bf16 MFMA ----------------
// R9: R8 body unchanged; ONLY the block->qtile mapping changed.
// R8 regression diagnosis: 512 blocks = exactly 2/CU with heavy-first
// weight-SORTED order -> co-resident pairs had EQUAL weight; worst CUs ran
// 2x qtile=15 (64 concurrent iter-units) while light CUs idled (occupancy
// 13.9%, makespan ~64 vs balanced 34). Steady-state rate was actually better
// than R7 (LDS-per-FLOP halved), the tail ate it.
// Fix: complementary co-residency. Practical dispatch puts bid k and bid
// k+256 on the same CU; map bids [0,256) -> heavy member (qtile 15-pr) and
// [256,512) -> light complement (qtile pr). Every CU then hosts (15-pr, pr):
// concurrent work sums to a uniform 34 iters. Speed-only heuristic (like XCD
// swizzle): a different dispatch mapping only costs balance, never correctness.
__global__ __launch_bounds__(256, 2) void attn_fwd(const u16* __restrict__ Q,
                                                   const u16* __restrict__ Kg,
                                                   const u16* __restrict__ Vt,
                                                   u16* __restrict__ O) {
  __shared__ u16 Ks[2][64 * 128];   // K rows (s-major, d contig), slot-swizzled
  __shared__ u16 Vts[2][128 * 64];  // V^T rows (d-major, s contig), slot-swizzled
  __shared__ u16 Ps[128 * 64];      // P round-trip (wave-private rows), slot-swizzled
  const int tid = threadIdx.x;
  const int w = tid >> 6, lane = tid & 63, quad = lane >> 4, c = lane & 15;
  const int c7 = (c & 7) * 8;       // read-side XOR (row%8 == c%8 for all frag reads)
  const int bid = blockIdx.x;
  // complementary co-residency mapping (see header comment)
  const int half = bid >> 8;          // 0 = heavy half, 1 = light half
  const int sub = bid & 255;          // (pr, b, h)
  const int pr = sub >> 5;            // 0..7
  const int h = sub & 15;
  const int b = (sub >> 4) & 1;
  const int qtile = half ? pr : (15 - pr);
  const int q0 = qtile * 128;
  const int wr0 = q0 + w * 32;              // this wave's first Q row
  const int jmax_blk = 2 * qtile + 1;       // last K tile any wave needs
  const int jmax_w = (wr0 + 31) >> 6;       // last K tile THIS wave needs

  // Q fragments in registers: rows wr0 + mi*16 + c (A-layout)
  s16x8 qf[2][4];
#pragma unroll
  for (int mi = 0; mi < 2; ++mi) {
    const u16* qbase = Q + ((size_t)(b * T_ + wr0 + mi * 16 + c) * H_ + h) * HD_;
#pragma unroll
    for (int kk = 0; kk < 4; ++kk) qf[mi][kk] = *(const s16x8*)(qbase + kk * 32 + quad * 8);
  }

  f32x4 of[2][8];
#pragma unroll
  for (int mi = 0; mi < 2; ++mi)
#pragma unroll
    for (int i = 0; i < 8; ++i) of[mi][i] = (f32x4){0.f, 0.f, 0.f, 0.f};
  float m_i[2][4], lp[2][4];
#pragma unroll
  for (int mi = 0; mi < 2; ++mi)
#pragma unroll
    for (int r = 0; r < 4; ++r) { m_i[mi][r] = -1e30f; lp[mi][r] = 0.f; }

  const u16* kbase = Kg + ((size_t)b * T_ * H_ + h) * HD_;
  const u16* vtbase = Vt + (size_t)(h * HD_) * (B_ * T_) + (size_t)b * T_;

  auto STAGE = [&](int j, int buf) {
    const u16* krow = kbase + (size_t)(j * 64) * KVSTRIDE_;
    const u16* vrow = vtbase + j * 64;
#pragma unroll
    for (int i = 0; i < 4; ++i) {
      int chunk = i * 256 + tid;  // 0..1023
      int krowi = chunk >> 4, kslot = (chunk & 15) ^ (krowi & 7);
      gload16(krow + (size_t)krowi * KVSTRIDE_ + kslot * 8, (void*)(&Ks[buf][0] + chunk * 8));
      int vrowi = chunk >> 3, vslot = (chunk & 7) ^ (vrowi & 7);
      gload16(vrow + (size_t)vrowi * (B_ * T_) + vslot * 8, (void*)(&Vts[buf][0] + chunk * 8));
    }
  };

  STAGE(0, 0);
  __syncthreads();  // vmcnt(0) drain -> tile 0 ready
  int cur = 0;

  for (int j = 0; j <= jmax_blk; ++j) {
    if (j < jmax_blk) STAGE(j + 1, cur ^ 1);

    if (j <= jmax_w) {  // wave-uniform: waves 0-1 skip the block's last tile
      // S = Q K^T : 16 Ks frag reads feed 32 MFMA (both mi)
      f32x4 sf[2][4];
#pragma unroll
      for (int mi = 0; mi < 2; ++mi)
#pragma unroll
        for (int ni = 0; ni < 4; ++ni) sf[mi][ni] = (f32x4){0.f, 0.f, 0.f, 0.f};
#pragma unroll
      for (int ni = 0; ni < 4; ++ni)
#pragma unroll
        for (int kk = 0; kk < 4; ++kk) {
          s16x8 bfr = *(const s16x8*)(&Ks[cur][(ni * 16 + c) * 128 + ((kk * 32 + quad * 8) ^ c7)]);
#pragma unroll
          for (int mi = 0; mi < 2; ++mi)
            sf[mi][ni] = __builtin_amdgcn_mfma_f32_16x16x32_bf16(qf[mi][kk], bfr, sf[mi][ni], 0, 0, 0);
        }
      // causal mask: only possible at this wave's diagonal tile
      if (j == jmax_w) {
#pragma unroll
        for (int mi = 0; mi < 2; ++mi)
#pragma unroll
          for (int ni = 0; ni < 4; ++ni)
#pragma unroll
            for (int r = 0; r < 4; ++r) {
              int rowg = wr0 + mi * 16 + quad * 4 + r;
              int colg = j * 64 + ni * 16 + c;
              if (colg > rowg) sf[mi][ni][r] = -1e30f;
            }
      }
      // online softmax per row-group (rows live across the 16 c-lanes)
#pragma unroll
      for (int mi = 0; mi < 2; ++mi) {
        float mc[4];
#pragma unroll
        for (int r = 0; r < 4; ++r)
          mc[r] = fmaxf(fmaxf(sf[mi][0][r], sf[mi][1][r]), fmaxf(sf[mi][2][r], sf[mi][3][r]));
#pragma unroll
        for (int off = 1; off < 16; off <<= 1)
#pragma unroll
          for (int r = 0; r < 4; ++r) mc[r] = fmaxf(mc[r], __shfl_xor(mc[r], off, 64));
#pragma unroll
        for (int r = 0; r < 4; ++r) {
          float mnew = fmaxf(m_i[mi][r], mc[r]);
          float alpha = __expf(m_i[mi][r] - mnew);
          m_i[mi][r] = mnew;
          lp[mi][r] *= alpha;
#pragma unroll
          for (int ot = 0; ot < 8; ++ot) of[mi][ot][r] *= alpha;
        }
#pragma unroll
        for (int ni = 0; ni < 4; ++ni)
#pragma unroll
          for (int r = 0; r < 4; ++r) {
            float p = __expf(sf[mi][ni][r] - m_i[mi][r]);
            sf[mi][ni][r] = p;
            lp[mi][r] += p;
          }
        // write P (local rows w*32+mi*16+quad*4+r), swizzled; wave-private -> no barrier
#pragma unroll
        for (int ni = 0; ni < 4; ++ni)
#pragma unroll
          for (int r = 0; r < 4; ++r) {
            int row = w * 32 + mi * 16 + quad * 4 + r;
            Ps[row * 64 + ((ni * 16 + c) ^ ((row & 7) * 8))] = f2bf(sf[mi][ni][r]);
          }
      }
      // O += P V : 16 Vts frag reads feed 32 MFMA (both mi)
      s16x8 pa[2][2];
#pragma unroll
      for (int mi = 0; mi < 2; ++mi) {
        int prow = w * 32 + mi * 16 + c;
        pa[mi][0] = *(const s16x8*)(&Ps[prow * 64 + ((quad * 8) ^ c7)]);
        pa[mi][1] = *(const s16x8*)(&Ps[prow * 64 + ((32 + quad * 8) ^ c7)]);
      }
#pragma unroll
      for (int ot = 0; ot < 8; ++ot)
#pragma unroll
        for (int kk = 0; kk < 2; ++kk) {
          s16x8 vfr = *(const s16x8*)(&Vts[cur][(ot * 16 + c) * 64 + ((kk * 32 + quad * 8) ^ c7)]);
#pragma unroll
          for (int mi = 0; mi < 2; ++mi)
            of[mi][ot] = __builtin_amdgcn_mfma_f32_16x16x32_bf16(pa[mi][kk], vfr, of[mi][ot], 0, 0, 0);
        }
    }

    __syncthreads();  // drains prefetch (covered by compute) + fences buf reuse
    cur ^= 1;
  }

  // epilogue: reduce l partials, O /= l, store bf16 ctx (flat (B,T,H,HD))
#pragma unroll
  for (int off = 1; off < 16; off <<= 1)
#pragma unroll
    for (int mi = 0; mi < 2; ++mi)
#pragma unroll
      for (int r = 0; r < 4; ++r) lp[mi][r] += __shfl_xor(lp[mi][r], off, 64);
#pragma unroll
  for (int mi = 0; mi < 2; ++mi) {
    float inv[4];
#pragma unroll
    for (int r = 0; r < 4; ++r) inv[r] = 1.0f / lp[mi][r];
    u16* obase = O + ((size_t)(b * T_ + wr0 + mi * 16) * H_ + h) * HD_;
#pragma unroll
    for (int ot = 0; ot < 8; ++ot)
#pragma unroll
      for (int r = 0; r < 4; ++r)
        obase[(size_t)(quad * 4 + r) * KVSTRIDE_ + ot * 16 + c] = f2bf(of[mi][ot][r] * inv[r]);
  }
}

// ---------------- launch ----------------
extern "C" void kernel_launch(void* const* d_in, const int* in_sizes, int n_in,
                              void* d_out, int out_size, void* d_ws, size_t ws_size,
                              hipStream_t stream) {
  const float* x = (const float*)d_in[0];
  const float* Wq = (const float*)d_in[1];
  const float* Wk = (const float*)d_in[2];
  const float* Wv = (const float*)d_in[3];
  const float* Wo = (const float*)d_in[4];
  const float* qw = (const float*)d_in[5];
  const float* kw = (const float*)d_in[6];
  float* out = (float*)d_out;

  const size_t xE = (size_t)B_ * T_ * D_;   // 8388608
  const size_t wE = (size_t)D_ * H_ * HD_;  // 4194304
  const size_t need = xE * 2 * 5 + wE * 2 * 4;  // ~112 MB
  if (ws_size < need) return;

  char* ws = (char*)d_ws;
  u16* xb = (u16*)ws;    ws += xE * 2;
  u16* wqkb = (u16*)ws;  ws += wE * 2 * 2;  // Wq || Wk adjacent -> one fused GEMM
  u16* wvb = (u16*)ws;   ws += wE * 2;
  u16* wob = (u16*)ws;   ws += wE * 2;
  u16* qb = (u16*)ws;    ws += xE * 2;
  u16* kb = (u16*)ws;    ws += xE * 2;
  u16* vtb = (u16*)ws;   ws += xE * 2;   // V^T: [H*HD][B*T]
  u16* ctxb = (u16*)ws;  ws += xE * 2;

  // single fused cast launch (x, Wq, Wk, Wv, Wo)
  cvt_all<<<24576, 256, 0, stream>>>(x, Wq, Wk, Wv, Wo, xb, wqkb, wvb, wob);

  // fused QK GEMM: C[4096 tok][4096] = xb * (Wq||Wk)^T, split into qb/kb
  dim3 gqk(32, 32);
  gemm_btn<2><<<gqk, 256, 0, stream>>>(xb, wqkb, qb, kb, 4096, 4096, 2048);
  // V^T = Wv * x^T : M=2048 (o), N=4096 (tokens)
  dim3 ggv(32, 16);
  gemm_btn<1><<<ggv, 256, 0, stream>>>(wvb, xb, vtb, nullptr, 2048, 4096, 2048);

  // fused q+k rmsnorm/rope (1 launch)
  rmsnorm_rope2<<<32768, 256, 0, stream>>>(qb, kb, qw, kw);

  attn_fwd<<<B_ * H_ * (T_ / 128), 256, 0, stream>>>(qb, kb, vtb, ctxb);

  dim3 gg(16, 32);
  gemm_btn<0><<<gg, 256, 0, stream>>>(ctxb, wob, out, nullptr, 4096, 2048, 2048);
}

// Round 8
// 374.595 us; speedup vs baseline: 1.1036x; 1.0389x over previous
//
#include <hip/hip_runtime.h>
#include <cstdint>
#include <cstddef>

#define B_ 2
#define T_ 2048
#define D_ 2048
#define H_ 16
#define HD_ 128
#define EPS_ 1e-6f
#define QSCALE_ 0.08838834764831845f  // 1/sqrt(128)
#define KVSTRIDE_ (H_ * HD_)          // 2048 elems between consecutive t

typedef unsigned short u16;
typedef short s16x8 __attribute__((ext_vector_type(8)));
typedef float f32x4 __attribute__((ext_vector_type(4)));

__device__ __forceinline__ float bf2f(u16 h) {
  union { unsigned int u; float f; } v;
  v.u = ((unsigned int)h) << 16;
  return v.f;
}
__device__ __forceinline__ u16 f2bf(float f) {
  union { float f; unsigned int u; } v;
  v.f = f;
  unsigned int r = v.u + 0x7FFFu + ((v.u >> 16) & 1u);  // round-to-nearest-even
  return (u16)(r >> 16);
}

// async global->LDS, 16B per lane (LDS dest = wave-uniform base + lane*16)
__device__ __forceinline__ void gload16(const void* g, void* l) {
  __builtin_amdgcn_global_load_lds(
      (const __attribute__((address_space(1))) unsigned int*)g,
      (__attribute__((address_space(3))) unsigned int*)l, 16, 0, 0);
}

// ---------------- fused fp32 -> bf16 cast of all 5 tensors (1 launch) ----------------
__global__ void cvt_all(const float* __restrict__ x, const float* __restrict__ Wq,
                        const float* __restrict__ Wk, const float* __restrict__ Wv,
                        const float* __restrict__ Wo, u16* __restrict__ xb,
                        u16* __restrict__ wqkb, u16* __restrict__ wvb, u16* __restrict__ wob) {
  const int XQ = 2097152, WQ = 1048576;
  int i = blockIdx.x * blockDim.x + threadIdx.x;
  const float* src;
  u16* dst;
  int off;
  if (i < XQ) { src = x; dst = xb; off = i; }
  else if (i < XQ + WQ) { src = Wq; dst = wqkb; off = i - XQ; }
  else if (i < XQ + 2 * WQ) { src = Wk; dst = wqkb + (size_t)WQ * 4; off = i - XQ - WQ; }
  else if (i < XQ + 3 * WQ) { src = Wv; dst = wvb; off = i - XQ - 2 * WQ; }
  else { src = Wo; dst = wob; off = i - XQ - 3 * WQ; }
  float4 v = ((const float4*)src)[off];
  ((ushort4*)dst)[off] = make_ushort4(f2bf(v.x), f2bf(v.y), f2bf(v.z), f2bf(v.w));
}

// ---------------- bf16 GEMM: C[M,N] = A[M,K] * Bm[N,K]^T (R7 counted-vmcnt) ----------------
// counted-vmcnt 2-tiles-ahead pipeline (T4):
//   prologue: STAGE(0,b0); STAGE(1,b1); vmcnt(8); bar
//   iter t:   ds_read frags(buf[t&1]); lgkmcnt(0); bar; STAGE(t+2 -> buf[t&1]);
//             32x MFMA; vmcnt(8) [t+1 landed, t+2 in flight]; bar
// MODE: 0 = f32 out, 1 = bf16 out, 2 = QK-split (bf16; n0<2048 -> Cout,
// else Cout2 with col-2048; both stride 2048). n0 is block-uniform.
template <int MODE>
__global__ __launch_bounds__(256, 2) void gemm_btn(const u16* __restrict__ A,
                                                   const u16* __restrict__ Bm,
                                                   void* __restrict__ Cout,
                                                   void* __restrict__ Cout2,
                                                   int M, int N, int K) {
  __shared__ u16 As[2][2 * 128 * 32];
  __shared__ u16 Bs[2][2 * 128 * 32];
  const int tid = threadIdx.x;
  const int w = tid >> 6, lane = tid & 63, quad = lane >> 4, c = lane & 15;
  const int wm = w & 1, wn = w >> 1;
  const int m0 = blockIdx.y * 128, n0 = blockIdx.x * 128;
  const int NT = K >> 6;  // always 32 here (K=2048)

  f32x4 acc[4][4];
#pragma unroll
  for (int i = 0; i < 4; ++i)
#pragma unroll
    for (int j = 0; j < 4; ++j) acc[i][j] = (f32x4){0.f, 0.f, 0.f, 0.f};

  // 8 global_load_lds per thread => per-wave vmcnt +8 per STAGE.
  auto STAGE = [&](int t, int buf) {
    int k0 = t << 6;
#pragma unroll
    for (int i = 0; i < 4; ++i) {
      int chunk = (w * 4 + i) * 64 + lane;    // 0..1023
      int kc = chunk >> 9;                    // half-tile select (LDS-contiguous)
      int within = chunk & 511;
      int row = within >> 2, cc = within & 3; // 128 rows x 4 8-elem chunks
      gload16(A + (size_t)(m0 + row) * K + k0 + kc * 32 + cc * 8, (void*)(&As[buf][0] + chunk * 8));
      gload16(Bm + (size_t)(n0 + row) * K + k0 + kc * 32 + cc * 8, (void*)(&Bs[buf][0] + chunk * 8));
    }
  };

  STAGE(0, 0);
  STAGE(1, 1);
  asm volatile("s_waitcnt vmcnt(8)" ::: "memory");  // tile 0 landed (tile 1 in flight)
  __builtin_amdgcn_s_barrier();

  for (int t = 0; t < NT; ++t) {
    const int cur = t & 1;
    s16x8 af[4][2], bf[4][2];
#pragma unroll
    for (int kc = 0; kc < 2; ++kc) {
#pragma unroll
      for (int mi = 0; mi < 4; ++mi)
        af[mi][kc] = *(const s16x8*)(&As[cur][0] + kc * 4096 + (wm * 64 + mi * 16 + c) * 32 + quad * 8);
#pragma unroll
      for (int ni = 0; ni < 4; ++ni)
        bf[ni][kc] = *(const s16x8*)(&Bs[cur][0] + kc * 4096 + (wn * 64 + ni * 16 + c) * 32 + quad * 8);
    }
    // all reads of buf[cur] retired before any wave's DMA may overwrite it
    asm volatile("s_waitcnt lgkmcnt(0)" ::: "memory");
    __builtin_amdgcn_s_barrier();
    if (t + 2 < NT) STAGE(t + 2, cur);  // 2 tiles ahead into the freed buffer

#pragma unroll
    for (int kc = 0; kc < 2; ++kc)
#pragma unroll
      for (int mi = 0; mi < 4; ++mi)
#pragma unroll
        for (int ni = 0; ni < 4; ++ni)
          acc[mi][ni] = __builtin_amdgcn_mfma_f32_16x16x32_bf16(af[mi][kc], bf[ni][kc], acc[mi][ni], 0, 0, 0);

    if (t + 1 < NT) {
      if (t + 2 < NT)
        asm volatile("s_waitcnt vmcnt(8)" ::: "memory");  // tile t+1 landed, t+2 in flight
      else
        asm volatile("s_waitcnt vmcnt(0)" ::: "memory");  // last refill: full drain
      __builtin_amdgcn_s_barrier();
    }
  }

  // epilogue (no outstanding DMA: drained at t=NT-2)
  u16* dst16 = (u16*)Cout;
  int coloff = 0, nstride = N;
  if (MODE == 2) {
    nstride = 2048;
    if (n0 >= 2048) { dst16 = (u16*)Cout2; coloff = -2048; }
  }
#pragma unroll
  for (int mi = 0; mi < 4; ++mi)
#pragma unroll
    for (int ni = 0; ni < 4; ++ni)
#pragma unroll
      for (int r = 0; r < 4; ++r) {
        int row = m0 + wm * 64 + mi * 16 + quad * 4 + r;
        int col = n0 + wn * 64 + ni * 16 + c + coloff;
        float v = acc[mi][ni][r];
        if (MODE == 0)
          ((float*)Cout)[(size_t)row * N + col] = v;
        else
          dst16[(size_t)row * nstride + col] = f2bf(v);
      }
}

// ---------------- RMSNorm + interleaved RoPE for K only (Q is fused into attn) ----------------
__global__ void rmsnorm_rope_k(u16* __restrict__ kx, const float* __restrict__ kw) {
  const int tid = threadIdx.x;
  const int w = tid >> 6, lane = tid & 63;
  const int vec = blockIdx.x * 4 + w;   // (b*T + t)*H + h
  const int t = (vec >> 4) & (T_ - 1);  // /H % T
  u16* base = kx + (size_t)vec * HD_;
  unsigned int pk = *(const unsigned int*)(base + lane * 2);
  float e = bf2f((u16)(pk & 0xFFFFu));
  float o = bf2f((u16)(pk >> 16));
  float ss = e * e + o * o;
#pragma unroll
  for (int off = 1; off < 64; off <<= 1) ss += __shfl_xor(ss, off, 64);
  float rn = rsqrtf(ss * (1.0f / HD_) + EPS_);
  float we = kw[lane * 2], wo = kw[lane * 2 + 1];
  e = e * rn * we;
  o = o * rn * wo;
  float freq = expf(-(float)lane * (9.210340371976184f / 64.0f));  // 10000^(-lane/64)
  float ang = (float)t * freq;
  float sn, cs;
  sincosf(ang, &sn, &cs);
  float re = e * cs - o * sn;
  float ro = e * sn + o * cs;
  *(unsigned int*)(base + lane * 2) = ((unsigned int)f2bf(ro) << 16) | (unsigned int)f2bf(re);
}

// ---------------- causal flash attention, Br=Bc=64, bf16 MFMA ----------------
// R10: R7 body restored (Br=64, 1024 blocks: backfill slack self-balances the
// causal imbalance -- R8/R9 taught that 2 blocks/CU with no backfill pins the
// makespan on the longest chain). Plus:
//  - fused Q rmsnorm+RoPE at Q-frag load (each Q row read by exactly ONE block;
//    identical f32 op order + f2bf rounding as the standalone kernel)
//  - T5 setprio(1) around both MFMA clusters (m191 regime: many independent
//    blocks/CU, latency-bound -> +4-7%)
// Kept: XOR slot-swizzle, DMA staging w/ inverse-swizzled source, wave-private
// Ps, 2-phase prefetch, deferred l-reduction, launch_bounds(256,2).
__global__ __launch_bounds__(256, 2) void attn_fwd(const u16* __restrict__ Q,
                                                   const u16* __restrict__ Kg,
                                                   const u16* __restrict__ Vt,
                                                   u16* __restrict__ O,
                                                   const float* __restrict__ qw) {
  __shared__ u16 Ks[2][64 * 128];   // K rows (s-major, d contig), slot-swizzled
  __shared__ u16 Vts[2][128 * 64];  // V^T rows (d-major, s contig), slot-swizzled
  __shared__ u16 Ps[64 * 64];       // P round-trip (wave-private), slot-swizzled
  const int tid = threadIdx.x;
  const int w = tid >> 6, lane = tid & 63, quad = lane >> 4, c = lane & 15;
  const int c7 = (c & 7) * 8;    // read-side XOR term (row%8 == c%8 for all frag reads)
  const int bid = blockIdx.x;
  const int qt = 31 - (bid >> 5);  // heavy (qt=31) blocks dispatch first
  const int h = bid & 15;
  const int b = (bid >> 4) & 1;
  const int q0 = qt * 64;

  // ---- Q fragment load + FUSED rmsnorm/RoPE (rows w*16+c, A-layout) ----
  const int trow = q0 + w * 16 + c;  // token within T (this lane's Q row)
  const u16* qbase = Q + ((size_t)(b * T_ + trow) * H_ + h) * HD_;
  s16x8 qraw[4];
#pragma unroll
  for (int kk = 0; kk < 4; ++kk) qraw[kk] = *(const s16x8*)(qbase + kk * 32 + quad * 8);
  // row sum-of-squares: lane holds 32 of 128 elems; quads of the same c share a row
  float qv[4][8];
  float ss = 0.f;
#pragma unroll
  for (int kk = 0; kk < 4; ++kk)
#pragma unroll
    for (int e = 0; e < 8; ++e) {
      float v = bf2f((u16)qraw[kk][e]);
      qv[kk][e] = v;
      ss += v * v;
    }
  ss += __shfl_xor(ss, 16, 64);
  ss += __shfl_xor(ss, 32, 64);
  float rn = rsqrtf(ss * (1.0f / HD_) + EPS_);
  s16x8 qf[4];
#pragma unroll
  for (int kk = 0; kk < 4; ++kk)
#pragma unroll
    for (int p = 0; p < 4; ++p) {
      int idx = kk * 32 + quad * 8 + 2 * p;       // even dim index in [0,128)
      float e0 = qv[kk][2 * p] * rn * qw[idx];
      float o0 = qv[kk][2 * p + 1] * rn * qw[idx + 1];
      float freq = expf(-(float)(idx >> 1) * (9.210340371976184f / 64.0f));
      float ang = (float)trow * freq;
      float sn, cs;
      sincosf(ang, &sn, &cs);
      qf[kk][2 * p] = (short)f2bf((e0 * cs - o0 * sn) * QSCALE_);
      qf[kk][2 * p + 1] = (short)f2bf((e0 * sn + o0 * cs) * QSCALE_);
    }

  f32x4 of[8];
#pragma unroll
  for (int i = 0; i < 8; ++i) of[i] = (f32x4){0.f, 0.f, 0.f, 0.f};
  float m_i[4] = {-1e30f, -1e30f, -1e30f, -1e30f};
  float lp[4] = {0.f, 0.f, 0.f, 0.f};  // per-lane partial of l (reduced in epilogue)

  const u16* kbase = Kg + ((size_t)b * T_ * H_ + h) * HD_;
  const u16* vtbase = Vt + (size_t)(h * HD_) * (B_ * T_) + (size_t)b * T_;

  auto STAGE = [&](int j, int buf) {
    const u16* krow = kbase + (size_t)(j * 64) * KVSTRIDE_;
    const u16* vrow = vtbase + j * 64;
#pragma unroll
    for (int i = 0; i < 4; ++i) {
      int chunk = i * 256 + tid;  // 0..1023
      int krowi = chunk >> 4, kslot = (chunk & 15) ^ (krowi & 7);
      gload16(krow + (size_t)krowi * KVSTRIDE_ + kslot * 8, (void*)(&Ks[buf][0] + chunk * 8));
      int vrowi = chunk >> 3, vslot = (chunk & 7) ^ (vrowi & 7);
      gload16(vrow + (size_t)vrowi * (B_ * T_) + vslot * 8, (void*)(&Vts[buf][0] + chunk * 8));
    }
  };

  STAGE(0, 0);
  __syncthreads();  // vmcnt(0) drain -> tile 0 ready
  int cur = 0;

  for (int j = 0; j <= qt; ++j) {
    // issue NEXT tile's loads; they complete while we compute tile j
    if (j < qt) STAGE(j + 1, cur ^ 1);

    // S = Q K^T  (rows w*16+quad*4+r, cols ni*16+c); Ks row = ni*16+c -> row%8 == c%8
    f32x4 sf[4];
    __builtin_amdgcn_s_setprio(1);
#pragma unroll
    for (int ni = 0; ni < 4; ++ni) {
      f32x4 a = (f32x4){0.f, 0.f, 0.f, 0.f};
#pragma unroll
      for (int kk = 0; kk < 4; ++kk) {
        s16x8 bfr = *(const s16x8*)(&Ks[cur][(ni * 16 + c) * 128 + ((kk * 32 + quad * 8) ^ c7)]);
        a = __builtin_amdgcn_mfma_f32_16x16x32_bf16(qf[kk], bfr, a, 0, 0, 0);
      }
      sf[ni] = a;
    }
    __builtin_amdgcn_s_setprio(0);
    // causal mask (only needed on the diagonal tile)
    if (j == qt) {
#pragma unroll
      for (int ni = 0; ni < 4; ++ni)
#pragma unroll
        for (int r = 0; r < 4; ++r) {
          int rowg = w * 16 + quad * 4 + r;
          int colg = ni * 16 + c;
          if (colg > rowg) sf[ni][r] = -1e30f;
        }
    }
    // online softmax (rows live across 16 lanes sharing `quad`)
    float mc[4];
#pragma unroll
    for (int r = 0; r < 4; ++r)
      mc[r] = fmaxf(fmaxf(sf[0][r], sf[1][r]), fmaxf(sf[2][r], sf[3][r]));
#pragma unroll
    for (int off = 1; off < 16; off <<= 1)
#pragma unroll
      for (int r = 0; r < 4; ++r) mc[r] = fmaxf(mc[r], __shfl_xor(mc[r], off, 64));
#pragma unroll
    for (int r = 0; r < 4; ++r) {
      float mnew = fmaxf(m_i[r], mc[r]);
      float alpha = __expf(m_i[r] - mnew);
      m_i[r] = mnew;
      lp[r] *= alpha;
#pragma unroll
      for (int ot = 0; ot < 8; ++ot) of[ot][r] *= alpha;
    }
    // p values + LOCAL l partial (cross-lane sum deferred to epilogue)
#pragma unroll
    for (int ni = 0; ni < 4; ++ni)
#pragma unroll
      for (int r = 0; r < 4; ++r) {
        float p = __expf(sf[ni][r] - m_i[r]);
        sf[ni][r] = p;
        lp[r] += p;
      }
    // write P (C-layout -> LDS, rows w*16+quad*4+r), swizzled; wave-private
#pragma unroll
    for (int ni = 0; ni < 4; ++ni)
#pragma unroll
      for (int r = 0; r < 4; ++r) {
        int row = w * 16 + quad * 4 + r;
        Ps[row * 64 + ((ni * 16 + c) ^ ((row & 7) * 8))] = f2bf(sf[ni][r]);
      }
    // O += P V  (A-frag of P: rows w*16+c; B-frag of V from Vts)
    s16x8 pa[2];
    pa[0] = *(const s16x8*)(&Ps[(w * 16 + c) * 64 + ((quad * 8) ^ c7)]);
    pa[1] = *(const s16x8*)(&Ps[(w * 16 + c) * 64 + ((32 + quad * 8) ^ c7)]);
    __builtin_amdgcn_s_setprio(1);
#pragma unroll
    for (int ot = 0; ot < 8; ++ot) {
#pragma unroll
      for (int kk = 0; kk < 2; ++kk) {
        s16x8 vfr = *(const s16x8*)(&Vts[cur][(ot * 16 + c) * 64 + ((kk * 32 + quad * 8) ^ c7)]);
        of[ot] = __builtin_amdgcn_mfma_f32_16x16x32_bf16(pa[kk], vfr, of[ot], 0, 0, 0);
      }
    }
    __builtin_amdgcn_s_setprio(0);

    // single barrier per iteration: drains the prefetch (covered by compute)
    // and fences buf reuse across waves.
    __syncthreads();
    cur ^= 1;
  }

  // epilogue: reduce l partials across the 16 c-lanes, then O /= l, store bf16 ctx
#pragma unroll
  for (int off = 1; off < 16; off <<= 1)
#pragma unroll
    for (int r = 0; r < 4; ++r) lp[r] += __shfl_xor(lp[r], off, 64);
  float inv[4];
#pragma unroll
  for (int r = 0; r < 4; ++r) inv[r] = 1.0f / lp[r];
  u16* obase = O + ((size_t)(b * T_ + q0) * H_ + h) * HD_;
#pragma unroll
  for (int ot = 0; ot < 8; ++ot)
#pragma unroll
    for (int r = 0; r < 4; ++r)
      obase[(size_t)(w * 16 + quad * 4 + r) * KVSTRIDE_ + ot * 16 + c] = f2bf(of[ot][r] * inv[r]);
}

// ---------------- launch ----------------
extern "C" void kernel_launch(void* const* d_in, const int* in_sizes, int n_in,
                              void* d_out, int out_size, void* d_ws, size_t ws_size,
                              hipStream_t stream) {
  const float* x = (const float*)d_in[0];
  const float* Wq = (const float*)d_in[1];
  const float* Wk = (const float*)d_in[2];
  const float* Wv = (const float*)d_in[3];
  const float* Wo = (const float*)d_in[4];
  const float* qw = (const float*)d_in[5];
  const float* kw = (const float*)d_in[6];
  float* out = (float*)d_out;

  const size_t xE = (size_t)B_ * T_ * D_;   // 8388608
  const size_t wE = (size_t)D_ * H_ * HD_;  // 4194304
  const size_t need = xE * 2 * 5 + wE * 2 * 4;  // ~112 MB
  if (ws_size < need) return;

  char* ws = (char*)d_ws;
  u16* xb = (u16*)ws;    ws += xE * 2;
  u16* wqkb = (u16*)ws;  ws += wE * 2 * 2;  // Wq || Wk adjacent -> one fused GEMM
  u16* wvb = (u16*)ws;   ws += wE * 2;
  u16* wob = (u16*)ws;   ws += wE * 2;
  u16* qb = (u16*)ws;    ws += xE * 2;
  u16* kb = (u16*)ws;    ws += xE * 2;
  u16* vtb = (u16*)ws;   ws += xE * 2;   // V^T: [H*HD][B*T]
  u16* ctxb = (u16*)ws;  ws += xE * 2;

  // single fused cast launch (x, Wq, Wk, Wv, Wo)
  cvt_all<<<24576, 256, 0, stream>>>(x, Wq, Wk, Wv, Wo, xb, wqkb, wvb, wob);

  // fused QK GEMM: C[4096 tok][4096] = xb * (Wq||Wk)^T, split into qb/kb
  dim3 gqk(32, 32);
  gemm_btn<2><<<gqk, 256, 0, stream>>>(xb, wqkb, qb, kb, 4096, 4096, 2048);
  // V^T = Wv * x^T : M=2048 (o), N=4096 (tokens)
  dim3 ggv(32, 16);
  gemm_btn<1><<<ggv, 256, 0, stream>>>(wvb, xb, vtb, nullptr, 2048, 4096, 2048);

  // K-only rmsnorm/rope (Q's is fused into attn_fwd)
  rmsnorm_rope_k<<<16384, 256, 0, stream>>>(kb, kw);

  attn_fwd<<<B_ * H_ * (T_ / 64), 256, 0, stream>>>(qb, kb, vtb, ctxb, qw);

  dim3 gg(16, 32);
  gemm_btn<0><<<gg, 256, 0, stream>>>(ctxb, wob, out, nullptr, 4096, 2048, 2048);
}

// Round 9
// 373.967 us; speedup vs baseline: 1.1054x; 1.0017x over previous
//
#include <hip/hip_runtime.h>
#include <cstdint>
#include <cstddef>

#define B_ 2
#define T_ 2048
#define D_ 2048
#define H_ 16
#define HD_ 128
#define EPS_ 1e-6f
#define QSCALE_ 0.08838834764831845f  // 1/sqrt(128)
#define KVSTRIDE_ (H_ * HD_)          // 2048 elems between consecutive t

typedef unsigned short u16;
typedef short s16x8 __attribute__((ext_vector_type(8)));
typedef float f32x4 __attribute__((ext_vector_type(4)));

__device__ __forceinline__ float bf2f(u16 h) {
  union { unsigned int u; float f; } v;
  v.u = ((unsigned int)h) << 16;
  return v.f;
}
__device__ __forceinline__ u16 f2bf(float f) {
  union { float f; unsigned int u; } v;
  v.f = f;
  unsigned int r = v.u + 0x7FFFu + ((v.u >> 16) & 1u);  // round-to-nearest-even
  return (u16)(r >> 16);
}

// async global->LDS, 16B per lane (LDS dest = wave-uniform base + lane*16)
__device__ __forceinline__ void gload16(const void* g, void* l) {
  __builtin_amdgcn_global_load_lds(
      (const __attribute__((address_space(1))) unsigned int*)g,
      (__attribute__((address_space(3))) unsigned int*)l, 16, 0, 0);
}

// ---------------- fused fp32->bf16 cast of all 5 tensors + RoPE table (1 launch) ----------------
// R11: extra 512 blocks fill rope[t*64+fi] = (cos, sin)(t * 10000^(-fi/64)) with
// the SAME expf/sincosf sequence as the old in-kernel path (bitwise-identical
// numerics). 1 MB table, L2-resident; removes all trig from the hot kernels
// (Appendix-B: on-device trig turns memory-bound kernels VALU-bound).
__global__ void cvt_all(const float* __restrict__ x, const float* __restrict__ Wq,
                        const float* __restrict__ Wk, const float* __restrict__ Wv,
                        const float* __restrict__ Wo, u16* __restrict__ xb,
                        u16* __restrict__ wqkb, u16* __restrict__ wvb, u16* __restrict__ wob,
                        float2* __restrict__ rope) {
  const int XQ = 2097152, WQ = 1048576, CAST_END = XQ + 4 * WQ;  // 6291456
  int i = blockIdx.x * blockDim.x + threadIdx.x;
  if (i >= CAST_END) {
    int idx = i - CAST_END;  // 0..131071 : t in [0,2048) x fi in [0,64)
    if (idx < T_ * 64) {
      int t = idx >> 6, fi = idx & 63;
      float freq = expf(-(float)fi * (9.210340371976184f / 64.0f));  // 10000^(-fi/64)
      float ang = (float)t * freq;
      float sn, cs;
      sincosf(ang, &sn, &cs);
      rope[idx] = make_float2(cs, sn);
    }
    return;
  }
  const float* src;
  u16* dst;
  int off;
  if (i < XQ) { src = x; dst = xb; off = i; }
  else if (i < XQ + WQ) { src = Wq; dst = wqkb; off = i - XQ; }
  else if (i < XQ + 2 * WQ) { src = Wk; dst = wqkb + (size_t)WQ * 4; off = i - XQ - WQ; }
  else if (i < XQ + 3 * WQ) { src = Wv; dst = wvb; off = i - XQ - 2 * WQ; }
  else { src = Wo; dst = wob; off = i - XQ - 3 * WQ; }
  float4 v = ((const float4*)src)[off];
  ((ushort4*)dst)[off] = make_ushort4(f2bf(v.x), f2bf(v.y), f2bf(v.z), f2bf(v.w));
}

// ---------------- bf16 GEMM: C[M,N] = A[M,K] * Bm[N,K]^T (R7 counted-vmcnt) ----------------
// counted-vmcnt 2-tiles-ahead pipeline (T4):
//   prologue: STAGE(0,b0); STAGE(1,b1); vmcnt(8); bar
//   iter t:   ds_read frags(buf[t&1]); lgkmcnt(0); bar; STAGE(t+2 -> buf[t&1]);
//             32x MFMA; vmcnt(8) [t+1 landed, t+2 in flight]; bar
// MODE: 0 = f32 out, 1 = bf16 out, 2 = QK-split (bf16; n0<2048 -> Cout,
// else Cout2 with col-2048; both stride 2048). n0 is block-uniform.
template <int MODE>
__global__ __launch_bounds__(256, 2) void gemm_btn(const u16* __restrict__ A,
                                                   const u16* __restrict__ Bm,
                                                   void* __restrict__ Cout,
                                                   void* __restrict__ Cout2,
                                                   int M, int N, int K) {
  __shared__ u16 As[2][2 * 128 * 32];
  __shared__ u16 Bs[2][2 * 128 * 32];
  const int tid = threadIdx.x;
  const int w = tid >> 6, lane = tid & 63, quad = lane >> 4, c = lane & 15;
  const int wm = w & 1, wn = w >> 1;
  const int m0 = blockIdx.y * 128, n0 = blockIdx.x * 128;
  const int NT = K >> 6;  // always 32 here (K=2048)

  f32x4 acc[4][4];
#pragma unroll
  for (int i = 0; i < 4; ++i)
#pragma unroll
    for (int j = 0; j < 4; ++j) acc[i][j] = (f32x4){0.f, 0.f, 0.f, 0.f};

  // 8 global_load_lds per thread => per-wave vmcnt +8 per STAGE.
  auto STAGE = [&](int t, int buf) {
    int k0 = t << 6;
#pragma unroll
    for (int i = 0; i < 4; ++i) {
      int chunk = (w * 4 + i) * 64 + lane;    // 0..1023
      int kc = chunk >> 9;                    // half-tile select (LDS-contiguous)
      int within = chunk & 511;
      int row = within >> 2, cc = within & 3; // 128 rows x 4 8-elem chunks
      gload16(A + (size_t)(m0 + row) * K + k0 + kc * 32 + cc * 8, (void*)(&As[buf][0] + chunk * 8));
      gload16(Bm + (size_t)(n0 + row) * K + k0 + kc * 32 + cc * 8, (void*)(&Bs[buf][0] + chunk * 8));
    }
  };

  STAGE(0, 0);
  STAGE(1, 1);
  asm volatile("s_waitcnt vmcnt(8)" ::: "memory");  // tile 0 landed (tile 1 in flight)
  __builtin_amdgcn_s_barrier();

  for (int t = 0; t < NT; ++t) {
    const int cur = t & 1;
    s16x8 af[4][2], bf[4][2];
#pragma unroll
    for (int kc = 0; kc < 2; ++kc) {
#pragma unroll
      for (int mi = 0; mi < 4; ++mi)
        af[mi][kc] = *(const s16x8*)(&As[cur][0] + kc * 4096 + (wm * 64 + mi * 16 + c) * 32 + quad * 8);
#pragma unroll
      for (int ni = 0; ni < 4; ++ni)
        bf[ni][kc] = *(const s16x8*)(&Bs[cur][0] + kc * 4096 + (wn * 64 + ni * 16 + c) * 32 + quad * 8);
    }
    // all reads of buf[cur] retired before any wave's DMA may overwrite it
    asm volatile("s_waitcnt lgkmcnt(0)" ::: "memory");
    __builtin_amdgcn_s_barrier();
    if (t + 2 < NT) STAGE(t + 2, cur);  // 2 tiles ahead into the freed buffer

#pragma unroll
    for (int kc = 0; kc < 2; ++kc)
#pragma unroll
      for (int mi = 0; mi < 4; ++mi)
#pragma unroll
        for (int ni = 0; ni < 4; ++ni)
          acc[mi][ni] = __builtin_amdgcn_mfma_f32_16x16x32_bf16(af[mi][kc], bf[ni][kc], acc[mi][ni], 0, 0, 0);

    if (t + 1 < NT) {
      if (t + 2 < NT)
        asm volatile("s_waitcnt vmcnt(8)" ::: "memory");  // tile t+1 landed, t+2 in flight
      else
        asm volatile("s_waitcnt vmcnt(0)" ::: "memory");  // last refill: full drain
      __builtin_amdgcn_s_barrier();
    }
  }

  // epilogue (no outstanding DMA: drained at t=NT-2)
  u16* dst16 = (u16*)Cout;
  int coloff = 0, nstride = N;
  if (MODE == 2) {
    nstride = 2048;
    if (n0 >= 2048) { dst16 = (u16*)Cout2; coloff = -2048; }
  }
#pragma unroll
  for (int mi = 0; mi < 4; ++mi)
#pragma unroll
    for (int ni = 0; ni < 4; ++ni)
#pragma unroll
      for (int r = 0; r < 4; ++r) {
        int row = m0 + wm * 64 + mi * 16 + quad * 4 + r;
        int col = n0 + wn * 64 + ni * 16 + c + coloff;
        float v = acc[mi][ni][r];
        if (MODE == 0)
          ((float*)Cout)[(size_t)row * N + col] = v;
        else
          dst16[(size_t)row * nstride + col] = f2bf(v);
      }
}

// ---------------- RMSNorm + interleaved RoPE for K only (table-based trig) ----------------
__global__ void rmsnorm_rope_k(u16* __restrict__ kx, const float* __restrict__ kw,
                               const float2* __restrict__ rope) {
  const int tid = threadIdx.x;
  const int w = tid >> 6, lane = tid & 63;
  const int vec = blockIdx.x * 4 + w;   // (b*T + t)*H + h
  const int t = (vec >> 4) & (T_ - 1);  // /H % T
  u16* base = kx + (size_t)vec * HD_;
  unsigned int pk = *(const unsigned int*)(base + lane * 2);
  float e = bf2f((u16)(pk & 0xFFFFu));
  float o = bf2f((u16)(pk >> 16));
  float ss = e * e + o * o;
#pragma unroll
  for (int off = 1; off < 64; off <<= 1) ss += __shfl_xor(ss, off, 64);
  float rn = rsqrtf(ss * (1.0f / HD_) + EPS_);
  float we = kw[lane * 2], wo = kw[lane * 2 + 1];
  e = e * rn * we;
  o = o * rn * wo;
  float2 cn = rope[t * 64 + lane];  // (cos, sin)
  float re = e * cn.x - o * cn.y;
  float ro = e * cn.y + o * cn.x;
  *(unsigned int*)(base + lane * 2) = ((unsigned int)f2bf(ro) << 16) | (unsigned int)f2bf(re);
}

// ---------------- causal flash attention, Br=Bc=64, bf16 MFMA ----------------
// R11 vs R10 (attn regressed 84->98 there; counters split the blame 7+7 us):
//  - setprio REMOVED: 4 waves are barrier-locked per iter -> m190 (lockstep,
//    negative) regime, not m191. Priority starved the co-resident block's
//    STAGE issue (MfmaUtil 17.3->14.5).
//  - fused Q rmsnorm/RoPE kept, but trig now comes from the precomputed rope
//    table (VALUBusy showed +7 us of sincosf/expf VALU work; table loads are
//    L2-hits with identical numerics).
// Kept: R7 body (Br=64, 1024 blocks, backfill slack), XOR slot-swizzle, DMA
// staging w/ inverse-swizzled source, wave-private Ps, 2-phase prefetch,
// deferred l-reduction, launch_bounds(256,2).
__global__ __launch_bounds__(256, 2) void attn_fwd(const u16* __restrict__ Q,
                                                   const u16* __restrict__ Kg,
                                                   const u16* __restrict__ Vt,
                                                   u16* __restrict__ O,
                                                   const float* __restrict__ qw,
                                                   const float2* __restrict__ rope) {
  __shared__ u16 Ks[2][64 * 128];   // K rows (s-major, d contig), slot-swizzled
  __shared__ u16 Vts[2][128 * 64];  // V^T rows (d-major, s contig), slot-swizzled
  __shared__ u16 Ps[64 * 64];       // P round-trip (wave-private), slot-swizzled
  const int tid = threadIdx.x;
  const int w = tid >> 6, lane = tid & 63, quad = lane >> 4, c = lane & 15;
  const int c7 = (c & 7) * 8;    // read-side XOR term (row%8 == c%8 for all frag reads)
  const int bid = blockIdx.x;
  const int qt = 31 - (bid >> 5);  // heavy (qt=31) blocks dispatch first
  const int h = bid & 15;
  const int b = (bid >> 4) & 1;
  const int q0 = qt * 64;

  // ---- Q fragment load + FUSED rmsnorm/RoPE (rows w*16+c, A-layout) ----
  const int trow = q0 + w * 16 + c;  // token within T (this lane's Q row)
  const u16* qbase = Q + ((size_t)(b * T_ + trow) * H_ + h) * HD_;
  s16x8 qraw[4];
#pragma unroll
  for (int kk = 0; kk < 4; ++kk) qraw[kk] = *(const s16x8*)(qbase + kk * 32 + quad * 8);
  // row sum-of-squares: lane holds 32 of 128 elems; quads of the same c share a row
  float qv[4][8];
  float ss = 0.f;
#pragma unroll
  for (int kk = 0; kk < 4; ++kk)
#pragma unroll
    for (int e = 0; e < 8; ++e) {
      float v = bf2f((u16)qraw[kk][e]);
      qv[kk][e] = v;
      ss += v * v;
    }
  ss += __shfl_xor(ss, 16, 64);
  ss += __shfl_xor(ss, 32, 64);
  float rn = rsqrtf(ss * (1.0f / HD_) + EPS_);
  const float2* rrow = rope + trow * 64;
  const float2* qw2 = (const float2*)qw;
  s16x8 qf[4];
#pragma unroll
  for (int kk = 0; kk < 4; ++kk) {
    const float4* rp = (const float4*)(rrow + kk * 16 + quad * 4);
    float4 cs0 = rp[0];  // cos(p0),sin(p0),cos(p1),sin(p1)
    float4 cs1 = rp[1];  // cos(p2),sin(p2),cos(p3),sin(p3)
    float cosv[4] = {cs0.x, cs0.z, cs1.x, cs1.z};
    float sinv[4] = {cs0.y, cs0.w, cs1.y, cs1.w};
#pragma unroll
    for (int p = 0; p < 4; ++p) {
      int idx = kk * 32 + quad * 8 + 2 * p;   // even dim index in [0,128)
      float2 wv = qw2[idx >> 1];
      float e0 = qv[kk][2 * p] * rn * wv.x;
      float o0 = qv[kk][2 * p + 1] * rn * wv.y;
      qf[kk][2 * p] = (short)f2bf((e0 * cosv[p] - o0 * sinv[p]) * QSCALE_);
      qf[kk][2 * p + 1] = (short)f2bf((e0 * sinv[p] + o0 * cosv[p]) * QSCALE_);
    }
  }

  f32x4 of[8];
#pragma unroll
  for (int i = 0; i < 8; ++i) of[i] = (f32x4){0.f, 0.f, 0.f, 0.f};
  float m_i[4] = {-1e30f, -1e30f, -1e30f, -1e30f};
  float lp[4] = {0.f, 0.f, 0.f, 0.f};  // per-lane partial of l (reduced in epilogue)

  const u16* kbase = Kg + ((size_t)b * T_ * H_ + h) * HD_;
  const u16* vtbase = Vt + (size_t)(h * HD_) * (B_ * T_) + (size_t)b * T_;

  auto STAGE = [&](int j, int buf) {
    const u16* krow = kbase + (size_t)(j * 64) * KVSTRIDE_;
    const u16* vrow = vtbase + j * 64;
#pragma unroll
    for (int i = 0; i < 4; ++i) {
      int chunk = i * 256 + tid;  // 0..1023
      int krowi = chunk >> 4, kslot = (chunk & 15) ^ (krowi & 7);
      gload16(krow + (size_t)krowi * KVSTRIDE_ + kslot * 8, (void*)(&Ks[buf][0] + chunk * 8));
      int vrowi = chunk >> 3, vslot = (chunk & 7) ^ (vrowi & 7);
      gload16(vrow + (size_t)vrowi * (B_ * T_) + vslot * 8, (void*)(&Vts[buf][0] + chunk * 8));
    }
  };

  STAGE(0, 0);
  __syncthreads();  // vmcnt(0) drain -> tile 0 ready
  int cur = 0;

  for (int j = 0; j <= qt; ++j) {
    // issue NEXT tile's loads; they complete while we compute tile j
    if (j < qt) STAGE(j + 1, cur ^ 1);

    // S = Q K^T  (rows w*16+quad*4+r, cols ni*16+c); Ks row = ni*16+c -> row%8 == c%8
    f32x4 sf[4];
#pragma unroll
    for (int ni = 0; ni < 4; ++ni) {
      f32x4 a = (f32x4){0.f, 0.f, 0.f, 0.f};
#pragma unroll
      for (int kk = 0; kk < 4; ++kk) {
        s16x8 bfr = *(const s16x8*)(&Ks[cur][(ni * 16 + c) * 128 + ((kk * 32 + quad * 8) ^ c7)]);
        a = __builtin_amdgcn_mfma_f32_16x16x32_bf16(qf[kk], bfr, a, 0, 0, 0);
      }
      sf[ni] = a;
    }
    // causal mask (only needed on the diagonal tile)
    if (j == qt) {
#pragma unroll
      for (int ni = 0; ni < 4; ++ni)
#pragma unroll
        for (int r = 0; r < 4; ++r) {
          int rowg = w * 16 + quad * 4 + r;
          int colg = ni * 16 + c;
          if (colg > rowg) sf[ni][r] = -1e30f;
        }
    }
    // online softmax (rows live across 16 lanes sharing `quad`)
    float mc[4];
#pragma unroll
    for (int r = 0; r < 4; ++r)
      mc[r] = fmaxf(fmaxf(sf[0][r], sf[1][r]), fmaxf(sf[2][r], sf[3][r]));
#pragma unroll
    for (int off = 1; off < 16; off <<= 1)
#pragma unroll
      for (int r = 0; r < 4; ++r) mc[r] = fmaxf(mc[r], __shfl_xor(mc[r], off, 64));
#pragma unroll
    for (int r = 0; r < 4; ++r) {
      float mnew = fmaxf(m_i[r], mc[r]);
      float alpha = __expf(m_i[r] - mnew);
      m_i[r] = mnew;
      lp[r] *= alpha;
#pragma unroll
      for (int ot = 0; ot < 8; ++ot) of[ot][r] *= alpha;
    }
    // p values + LOCAL l partial (cross-lane sum deferred to epilogue)
#pragma unroll
    for (int ni = 0; ni < 4; ++ni)
#pragma unroll
      for (int r = 0; r < 4; ++r) {
        float p = __expf(sf[ni][r] - m_i[r]);
        sf[ni][r] = p;
        lp[r] += p;
      }
    // write P (C-layout -> LDS, rows w*16+quad*4+r), swizzled; wave-private
#pragma unroll
    for (int ni = 0; ni < 4; ++ni)
#pragma unroll
      for (int r = 0; r < 4; ++r) {
        int row = w * 16 + quad * 4 + r;
        Ps[row * 64 + ((ni * 16 + c) ^ ((row & 7) * 8))] = f2bf(sf[ni][r]);
      }
    // O += P V  (A-frag of P: rows w*16+c; B-frag of V from Vts)
    s16x8 pa[2];
    pa[0] = *(const s16x8*)(&Ps[(w * 16 + c) * 64 + ((quad * 8) ^ c7)]);
    pa[1] = *(const s16x8*)(&Ps[(w * 16 + c) * 64 + ((32 + quad * 8) ^ c7)]);
#pragma unroll
    for (int ot = 0; ot < 8; ++ot) {
#pragma unroll
      for (int kk = 0; kk < 2; ++kk) {
        s16x8 vfr = *(const s16x8*)(&Vts[cur][(ot * 16 + c) * 64 + ((kk * 32 + quad * 8) ^ c7)]);
        of[ot] = __builtin_amdgcn_mfma_f32_16x16x32_bf16(pa[kk], vfr, of[ot], 0, 0, 0);
      }
    }

    // single barrier per iteration: drains the prefetch (covered by compute)
    // and fences buf reuse across waves.
    __syncthreads();
    cur ^= 1;
  }

  // epilogue: reduce l partials across the 16 c-lanes, then O /= l, store bf16 ctx
#pragma unroll
  for (int off = 1; off < 16; off <<= 1)
#pragma unroll
    for (int r = 0; r < 4; ++r) lp[r] += __shfl_xor(lp[r], off, 64);
  float inv[4];
#pragma unroll
  for (int r = 0; r < 4; ++r) inv[r] = 1.0f / lp[r];
  u16* obase = O + ((size_t)(b * T_ + q0) * H_ + h) * HD_;
#pragma unroll
  for (int ot = 0; ot < 8; ++ot)
#pragma unroll
    for (int r = 0; r < 4; ++r)
      obase[(size_t)(w * 16 + quad * 4 + r) * KVSTRIDE_ + ot * 16 + c] = f2bf(of[ot][r] * inv[r]);
}

// ---------------- launch ----------------
extern "C" void kernel_launch(void* const* d_in, const int* in_sizes, int n_in,
                              void* d_out, int out_size, void* d_ws, size_t ws_size,
                              hipStream_t stream) {
  const float* x = (const float*)d_in[0];
  const float* Wq = (const float*)d_in[1];
  const float* Wk = (const float*)d_in[2];
  const float* Wv = (const float*)d_in[3];
  const float* Wo = (const float*)d_in[4];
  const float* qw = (const float*)d_in[5];
  const float* kw = (const float*)d_in[6];
  float* out = (float*)d_out;

  const size_t xE = (size_t)B_ * T_ * D_;   // 8388608
  const size_t wE = (size_t)D_ * H_ * HD_;  // 4194304
  const size_t ropeB = (size_t)T_ * 64 * sizeof(float2);  // 1 MB
  const size_t need = xE * 2 * 5 + wE * 2 * 4 + ropeB;  // ~113 MB
  if (ws_size < need) return;

  char* ws = (char*)d_ws;
  u16* xb = (u16*)ws;    ws += xE * 2;
  u16* wqkb = (u16*)ws;  ws += wE * 2 * 2;  // Wq || Wk adjacent -> one fused GEMM
  u16* wvb = (u16*)ws;   ws += wE * 2;
  u16* wob = (u16*)ws;   ws += wE * 2;
  u16* qb = (u16*)ws;    ws += xE * 2;
  u16* kb = (u16*)ws;    ws += xE * 2;
  u16* vtb = (u16*)ws;   ws += xE * 2;   // V^T: [H*HD][B*T]
  u16* ctxb = (u16*)ws;  ws += xE * 2;
  float2* rope = (float2*)ws; ws += ropeB;

  // single fused cast launch (x, Wq, Wk, Wv, Wo) + rope table fill
  cvt_all<<<25088, 256, 0, stream>>>(x, Wq, Wk, Wv, Wo, xb, wqkb, wvb, wob, rope);

  // fused QK GEMM: C[4096 tok][4096] = xb * (Wq||Wk)^T, split into qb/kb
  dim3 gqk(32, 32);
  gemm_btn<2><<<gqk, 256, 0, stream>>>(xb, wqkb, qb, kb, 4096, 4096, 2048);
  // V^T = Wv * x^T : M=2048 (o), N=4096 (tokens)
  dim3 ggv(32, 16);
  gemm_btn<1><<<ggv, 256, 0, stream>>>(wvb, xb, vtb, nullptr, 2048, 4096, 2048);

  // K-only rmsnorm/rope (Q's is fused into attn_fwd), table-based trig
  rmsnorm_rope_k<<<16384, 256, 0, stream>>>(kb, kw, rope);

  attn_fwd<<<B_ * H_ * (T_ / 64), 256, 0, stream>>>(qb, kb, vtb, ctxb, qw, rope);

  dim3 gg(16, 32);
  gemm_btn<0><<<gg, 256, 0, stream>>>(ctxb, wob, out, nullptr, 4096, 2048, 2048);
}

// Round 10
// 360.547 us; speedup vs baseline: 1.1466x; 1.0372x over previous
//
#include <hip/hip_runtime.h>
#include <cstdint>
#include <cstddef>

#define B_ 2
#define T_ 2048
#define D_ 2048
#define H_ 16
#define HD_ 128
#define EPS_ 1e-6f
#define QSCALE_ 0.08838834764831845f  // 1/sqrt(128)
#define KVSTRIDE_ (H_ * HD_)          // 2048 elems between consecutive t

typedef unsigned short u16;
typedef short s16x8 __attribute__((ext_vector_type(8)));
typedef float f32x4 __attribute__((ext_vector_type(4)));

__device__ __forceinline__ float bf2f(u16 h) {
  union { unsigned int u; float f; } v;
  v.u = ((unsigned int)h) << 16;
  return v.f;
}
__device__ __forceinline__ u16 f2bf(float f) {
  union { float f; unsigned int u; } v;
  v.f = f;
  unsigned int r = v.u + 0x7FFFu + ((v.u >> 16) & 1u);  // round-to-nearest-even
  return (u16)(r >> 16);
}

// async global->LDS, 16B per lane (LDS dest = wave-uniform base + lane*16)
__device__ __forceinline__ void gload16(const void* g, void* l) {
  __builtin_amdgcn_global_load_lds(
      (const __attribute__((address_space(1))) unsigned int*)g,
      (__attribute__((address_space(3))) unsigned int*)l, 16, 0, 0);
}

// ---------------- fused fp32->bf16 cast of all 5 tensors + RoPE table (1 launch) ----------------
// rope[t*64+fi] = (cos, sin)(t * 10000^(-fi/64)); 1 MB, L2-resident. All trig
// lives here; hot kernels only load float2 pairs.
__global__ void cvt_all(const float* __restrict__ x, const float* __restrict__ Wq,
                        const float* __restrict__ Wk, const float* __restrict__ Wv,
                        const float* __restrict__ Wo, u16* __restrict__ xb,
                        u16* __restrict__ wqkb, u16* __restrict__ wvb, u16* __restrict__ wob,
                        float2* __restrict__ rope) {
  const int XQ = 2097152, WQ = 1048576, CAST_END = XQ + 4 * WQ;  // 6291456
  int i = blockIdx.x * blockDim.x + threadIdx.x;
  if (i >= CAST_END) {
    int idx = i - CAST_END;  // 0..131071 : t in [0,2048) x fi in [0,64)
    if (idx < T_ * 64) {
      int t = idx >> 6, fi = idx & 63;
      float freq = expf(-(float)fi * (9.210340371976184f / 64.0f));  // 10000^(-fi/64)
      float ang = (float)t * freq;
      float sn, cs;
      sincosf(ang, &sn, &cs);
      rope[idx] = make_float2(cs, sn);
    }
    return;
  }
  const float* src;
  u16* dst;
  int off;
  if (i < XQ) { src = x; dst = xb; off = i; }
  else if (i < XQ + WQ) { src = Wq; dst = wqkb; off = i - XQ; }
  else if (i < XQ + 2 * WQ) { src = Wk; dst = wqkb + (size_t)WQ * 4; off = i - XQ - WQ; }
  else if (i < XQ + 3 * WQ) { src = Wv; dst = wvb; off = i - XQ - 2 * WQ; }
  else { src = Wo; dst = wob; off = i - XQ - 3 * WQ; }
  float4 v = ((const float4*)src)[off];
  ((ushort4*)dst)[off] = make_ushort4(f2bf(v.x), f2bf(v.y), f2bf(v.z), f2bf(v.w));
}

// ---------------- fused QK(+norm+rope) / V^T GEMM, one dispatch ----------------
// R12: grid (32, 48). y<32: C[4096 tok][4096] = xb*(Wq||Wk)^T with the RMSNorm
// + interleaved RoPE fused into the epilogue (each 128-col tile = one head's
// full HD; norm computed from the f32 accumulator -- closer to the f32
// reference than the old bf16-roundtrip path). y>=32: V^T = wvb * xb^T.
// Main loop = R7 counted-vmcnt 2-tiles-ahead pipeline (T4):
//   prologue: STAGE(0,b0); STAGE(1,b1); vmcnt(8); bar
//   iter t:   ds_read frags(buf[t&1]); lgkmcnt(0); bar; STAGE(t+2 -> buf[t&1]);
//             32x MFMA; vmcnt(8) [t+1 landed, t+2 in flight]; bar
// Epilogue QK norm: per-lane sum_ni acc^2 -> shfl over 16 c-lanes -> cross-wn
// pair via 1KB of reused As LDS (all As reads retired at the last in-loop
// barrier, so reuse is safe after one __syncthreads) -> rn -> weight -> rope
// (pair partner via shfl_xor(vn,1): pair cols differ only in bit 0) -> QSCALE
// for the Q half -> bf16 store.
__global__ __launch_bounds__(256, 2) void gemm_qkv(const u16* __restrict__ xb,
                                                   const u16* __restrict__ wqkb,
                                                   const u16* __restrict__ wvb,
                                                   u16* __restrict__ qb, u16* __restrict__ kb,
                                                   u16* __restrict__ vtb,
                                                   const float* __restrict__ qw,
                                                   const float* __restrict__ kw,
                                                   const float2* __restrict__ rope) {
  __shared__ u16 As[2][2 * 128 * 32];
  __shared__ u16 Bs[2][2 * 128 * 32];
  const int tid = threadIdx.x;
  const int w = tid >> 6, lane = tid & 63, quad = lane >> 4, c = lane & 15;
  const int wm = w & 1, wn = w >> 1;
  const bool isV = blockIdx.y >= 32;
  const u16* A = isV ? wvb : xb;
  const u16* Bm = isV ? xb : wqkb;
  const int m0 = (isV ? (blockIdx.y - 32) : blockIdx.y) * 128;
  const int n0 = blockIdx.x * 128;
  const int K = 2048, NT = 32;

  f32x4 acc[4][4];
#pragma unroll
  for (int i = 0; i < 4; ++i)
#pragma unroll
    for (int j = 0; j < 4; ++j) acc[i][j] = (f32x4){0.f, 0.f, 0.f, 0.f};

  // 8 global_load_lds per thread => per-wave vmcnt +8 per STAGE.
  auto STAGE = [&](int t, int buf) {
    int k0 = t << 6;
#pragma unroll
    for (int i = 0; i < 4; ++i) {
      int chunk = (w * 4 + i) * 64 + lane;    // 0..1023
      int kc = chunk >> 9;                    // half-tile select (LDS-contiguous)
      int within = chunk & 511;
      int row = within >> 2, cc = within & 3; // 128 rows x 4 8-elem chunks
      gload16(A + (size_t)(m0 + row) * K + k0 + kc * 32 + cc * 8, (void*)(&As[buf][0] + chunk * 8));
      gload16(Bm + (size_t)(n0 + row) * K + k0 + kc * 32 + cc * 8, (void*)(&Bs[buf][0] + chunk * 8));
    }
  };

  STAGE(0, 0);
  STAGE(1, 1);
  asm volatile("s_waitcnt vmcnt(8)" ::: "memory");  // tile 0 landed (tile 1 in flight)
  __builtin_amdgcn_s_barrier();

  for (int t = 0; t < NT; ++t) {
    const int cur = t & 1;
    s16x8 af[4][2], bf[4][2];
#pragma unroll
    for (int kc = 0; kc < 2; ++kc) {
#pragma unroll
      for (int mi = 0; mi < 4; ++mi)
        af[mi][kc] = *(const s16x8*)(&As[cur][0] + kc * 4096 + (wm * 64 + mi * 16 + c) * 32 + quad * 8);
#pragma unroll
      for (int ni = 0; ni < 4; ++ni)
        bf[ni][kc] = *(const s16x8*)(&Bs[cur][0] + kc * 4096 + (wn * 64 + ni * 16 + c) * 32 + quad * 8);
    }
    // all reads of buf[cur] retired before any wave's DMA may overwrite it
    asm volatile("s_waitcnt lgkmcnt(0)" ::: "memory");
    __builtin_amdgcn_s_barrier();
    if (t + 2 < NT) STAGE(t + 2, cur);  // 2 tiles ahead into the freed buffer

#pragma unroll
    for (int kc = 0; kc < 2; ++kc)
#pragma unroll
      for (int mi = 0; mi < 4; ++mi)
#pragma unroll
        for (int ni = 0; ni < 4; ++ni)
          acc[mi][ni] = __builtin_amdgcn_mfma_f32_16x16x32_bf16(af[mi][kc], bf[ni][kc], acc[mi][ni], 0, 0, 0);

    if (t + 1 < NT) {
      if (t + 2 < NT)
        asm volatile("s_waitcnt vmcnt(8)" ::: "memory");  // tile t+1 landed, t+2 in flight
      else
        asm volatile("s_waitcnt vmcnt(0)" ::: "memory");  // last refill: full drain
      __builtin_amdgcn_s_barrier();
    }
  }

  if (isV) {
    // V^T epilogue: plain bf16 store, vtb[o][token], stride 4096
#pragma unroll
    for (int mi = 0; mi < 4; ++mi)
#pragma unroll
      for (int ni = 0; ni < 4; ++ni)
#pragma unroll
        for (int r = 0; r < 4; ++r) {
          int row = m0 + wm * 64 + mi * 16 + quad * 4 + r;
          int col = n0 + wn * 64 + ni * 16 + c;
          vtb[(size_t)row * 4096 + col] = f2bf(acc[mi][ni][r]);
        }
    return;
  }

  // ---- QK epilogue: fused RMSNorm + RoPE ----
  // 1) per-lane partial sum of squares over this wave's 64 cols of each row
  float p[4][4];
#pragma unroll
  for (int mi = 0; mi < 4; ++mi)
#pragma unroll
    for (int r = 0; r < 4; ++r) {
      float s = 0.f;
#pragma unroll
      for (int ni = 0; ni < 4; ++ni) s += acc[mi][ni][r] * acc[mi][ni][r];
      p[mi][r] = s;
    }
#pragma unroll
  for (int off = 1; off < 16; off <<= 1)
#pragma unroll
    for (int mi = 0; mi < 4; ++mi)
#pragma unroll
      for (int r = 0; r < 4; ++r) p[mi][r] += __shfl_xor(p[mi][r], off, 64);
  // 2) cross-wn reduction via reused As LDS (float ssred[2][128])
  float* ssred = (float*)&As[0][0];
  if (c == 0) {
#pragma unroll
    for (int mi = 0; mi < 4; ++mi)
#pragma unroll
      for (int r = 0; r < 4; ++r)
        ssred[wn * 128 + wm * 64 + mi * 16 + quad * 4 + r] = p[mi][r];
  }
  __syncthreads();
  float rn_[4][4];
#pragma unroll
  for (int mi = 0; mi < 4; ++mi)
#pragma unroll
    for (int r = 0; r < 4; ++r) {
      int lr = wm * 64 + mi * 16 + quad * 4 + r;
      rn_[mi][r] = rsqrtf((ssred[lr] + ssred[128 + lr]) * (1.0f / HD_) + EPS_);
    }
  // 3) norm + rope + store (Q half scaled by QSCALE)
  const bool isQ = (n0 < 2048);
  const float* nw = isQ ? qw : kw;
  const float scl = isQ ? QSCALE_ : 1.0f;
  u16* dst = isQ ? qb : kb;
  const int nbase = n0 - (isQ ? 0 : 2048);
#pragma unroll
  for (int mi = 0; mi < 4; ++mi)
#pragma unroll
    for (int ni = 0; ni < 4; ++ni)
#pragma unroll
      for (int r = 0; r < 4; ++r) {
        int row = m0 + wm * 64 + mi * 16 + quad * 4 + r;
        int t = row & (T_ - 1);
        int col = nbase + wn * 64 + ni * 16 + c;  // [0,2048)
        int d = col & 127;
        float vn = acc[mi][ni][r] * rn_[mi][r] * nw[d];
        float partner = __shfl_xor(vn, 1, 64);    // pair col differs only in bit 0
        float2 cn = rope[t * 64 + (d >> 1)];
        // even d: e*cos - o*sin ; odd d: e*sin + o*cos  (e=even elem, o=odd elem)
        float res = (c & 1) ? (partner * cn.y + vn * cn.x) : (vn * cn.x - partner * cn.y);
        dst[(size_t)row * 2048 + col] = f2bf(res * scl);
      }
}

// ---------------- bf16 GEMM for Wo: C[M,N] = A[M,K]*Bm[N,K]^T, f32 out ----------------
__global__ __launch_bounds__(256, 2) void gemm_btn(const u16* __restrict__ A,
                                                   const u16* __restrict__ Bm,
                                                   float* __restrict__ Cout,
                                                   int M, int N, int K) {
  __shared__ u16 As[2][2 * 128 * 32];
  __shared__ u16 Bs[2][2 * 128 * 32];
  const int tid = threadIdx.x;
  const int w = tid >> 6, lane = tid & 63, quad = lane >> 4, c = lane & 15;
  const int wm = w & 1, wn = w >> 1;
  const int m0 = blockIdx.y * 128, n0 = blockIdx.x * 128;
  const int NT = K >> 6;

  f32x4 acc[4][4];
#pragma unroll
  for (int i = 0; i < 4; ++i)
#pragma unroll
    for (int j = 0; j < 4; ++j) acc[i][j] = (f32x4){0.f, 0.f, 0.f, 0.f};

  auto STAGE = [&](int t, int buf) {
    int k0 = t << 6;
#pragma unroll
    for (int i = 0; i < 4; ++i) {
      int chunk = (w * 4 + i) * 64 + lane;
      int kc = chunk >> 9;
      int within = chunk & 511;
      int row = within >> 2, cc = within & 3;
      gload16(A + (size_t)(m0 + row) * K + k0 + kc * 32 + cc * 8, (void*)(&As[buf][0] + chunk * 8));
      gload16(Bm + (size_t)(n0 + row) * K + k0 + kc * 32 + cc * 8, (void*)(&Bs[buf][0] + chunk * 8));
    }
  };

  STAGE(0, 0);
  STAGE(1, 1);
  asm volatile("s_waitcnt vmcnt(8)" ::: "memory");
  __builtin_amdgcn_s_barrier();

  for (int t = 0; t < NT; ++t) {
    const int cur = t & 1;
    s16x8 af[4][2], bf[4][2];
#pragma unroll
    for (int kc = 0; kc < 2; ++kc) {
#pragma unroll
      for (int mi = 0; mi < 4; ++mi)
        af[mi][kc] = *(const s16x8*)(&As[cur][0] + kc * 4096 + (wm * 64 + mi * 16 + c) * 32 + quad * 8);
#pragma unroll
      for (int ni = 0; ni < 4; ++ni)
        bf[ni][kc] = *(const s16x8*)(&Bs[cur][0] + kc * 4096 + (wn * 64 + ni * 16 + c) * 32 + quad * 8);
    }
    asm volatile("s_waitcnt lgkmcnt(0)" ::: "memory");
    __builtin_amdgcn_s_barrier();
    if (t + 2 < NT) STAGE(t + 2, cur);

#pragma unroll
    for (int kc = 0; kc < 2; ++kc)
#pragma unroll
      for (int mi = 0; mi < 4; ++mi)
#pragma unroll
        for (int ni = 0; ni < 4; ++ni)
          acc[mi][ni] = __builtin_amdgcn_mfma_f32_16x16x32_bf16(af[mi][kc], bf[ni][kc], acc[mi][ni], 0, 0, 0);

    if (t + 1 < NT) {
      if (t + 2 < NT)
        asm volatile("s_waitcnt vmcnt(8)" ::: "memory");
      else
        asm volatile("s_waitcnt vmcnt(0)" ::: "memory");
      __builtin_amdgcn_s_barrier();
    }
  }

#pragma unroll
  for (int mi = 0; mi < 4; ++mi)
#pragma unroll
    for (int ni = 0; ni < 4; ++ni)
#pragma unroll
      for (int r = 0; r < 4; ++r) {
        int row = m0 + wm * 64 + mi * 16 + quad * 4 + r;
        int col = n0 + wn * 64 + ni * 16 + c;
        Cout[(size_t)row * N + col] = acc[mi][ni][r];
      }
}

// ---------------- causal flash attention, Br=Bc=64, bf16 MFMA (R7 body, exact) ----------------
// Q arrives fully normed+roped+scaled from gemm_qkv. 1024 blocks, heavy-first
// (backfill slack self-balances causal imbalance -- R8/R9 lesson). No setprio
// (lockstep waves: m190 regime). XOR slot-swizzle + DMA staging w/ inverse-
// swizzled source; wave-private Ps; 2-phase prefetch; deferred l-reduction.
__global__ __launch_bounds__(256, 2) void attn_fwd(const u16* __restrict__ Q,
                                                   const u16* __restrict__ Kg,
                                                   const u16* __restrict__ Vt,
                                                   u16* __restrict__ O) {
  __shared__ u16 Ks[2][64 * 128];   // K rows (s-major, d contig), slot-swizzled
  __shared__ u16 Vts[2][128 * 64];  // V^T rows (d-major, s contig), slot-swizzled
  __shared__ u16 Ps[64 * 64];       // P round-trip (wave-private), slot-swizzled
  const int tid = threadIdx.x;
  const int w = tid >> 6, lane = tid & 63, quad = lane >> 4, c = lane & 15;
  const int c7 = (c & 7) * 8;    // read-side XOR term (row%8 == c%8 for all frag reads)
  const int bid = blockIdx.x;
  const int qt = 31 - (bid >> 5);  // heavy (qt=31) blocks dispatch first
  const int h = bid & 15;
  const int b = (bid >> 4) & 1;
  const int q0 = qt * 64;

  // Q fragments, kept in registers (rows w*16+c, A-layout)
  s16x8 qf[4];
  const u16* qbase = Q + ((size_t)(b * T_ + q0 + w * 16 + c) * H_ + h) * HD_;
#pragma unroll
  for (int kk = 0; kk < 4; ++kk) qf[kk] = *(const s16x8*)(qbase + kk * 32 + quad * 8);

  f32x4 of[8];
#pragma unroll
  for (int i = 0; i < 8; ++i) of[i] = (f32x4){0.f, 0.f, 0.f, 0.f};
  float m_i[4] = {-1e30f, -1e30f, -1e30f, -1e30f};
  float lp[4] = {0.f, 0.f, 0.f, 0.f};  // per-lane partial of l (reduced in epilogue)

  const u16* kbase = Kg + ((size_t)b * T_ * H_ + h) * HD_;
  const u16* vtbase = Vt + (size_t)(h * HD_) * (B_ * T_) + (size_t)b * T_;

  auto STAGE = [&](int j, int buf) {
    const u16* krow = kbase + (size_t)(j * 64) * KVSTRIDE_;
    const u16* vrow = vtbase + j * 64;
#pragma unroll
    for (int i = 0; i < 4; ++i) {
      int chunk = i * 256 + tid;  // 0..1023
      int krowi = chunk >> 4, kslot = (chunk & 15) ^ (krowi & 7);
      gload16(krow + (size_t)krowi * KVSTRIDE_ + kslot * 8, (void*)(&Ks[buf][0] + chunk * 8));
      int vrowi = chunk >> 3, vslot = (chunk & 7) ^ (vrowi & 7);
      gload16(vrow + (size_t)vrowi * (B_ * T_) + vslot * 8, (void*)(&Vts[buf][0] + chunk * 8));
    }
  };

  STAGE(0, 0);
  __syncthreads();  // vmcnt(0) drain -> tile 0 ready
  int cur = 0;

  for (int j = 0; j <= qt; ++j) {
    // issue NEXT tile's loads; they complete while we compute tile j
    if (j < qt) STAGE(j + 1, cur ^ 1);

    // S = Q K^T  (rows w*16+quad*4+r, cols ni*16+c); Ks row = ni*16+c -> row%8 == c%8
    f32x4 sf[4];
#pragma unroll
    for (int ni = 0; ni < 4; ++ni) {
      f32x4 a = (f32x4){0.f, 0.f, 0.f, 0.f};
#pragma unroll
      for (int kk = 0; kk < 4; ++kk) {
        s16x8 bfr = *(const s16x8*)(&Ks[cur][(ni * 16 + c) * 128 + ((kk * 32 + quad * 8) ^ c7)]);
        a = __builtin_amdgcn_mfma_f32_16x16x32_bf16(qf[kk], bfr, a, 0, 0, 0);
      }
      sf[ni] = a;
    }
    // causal mask (only needed on the diagonal tile)
    if (j == qt) {
#pragma unroll
      for (int ni = 0; ni < 4; ++ni)
#pragma unroll
        for (int r = 0; r < 4; ++r) {
          int rowg = w * 16 + quad * 4 + r;
          int colg = ni * 16 + c;
          if (colg > rowg) sf[ni][r] = -1e30f;
        }
    }
    // online softmax (rows live across 16 lanes sharing `quad`)
    float mc[4];
#pragma unroll
    for (int r = 0; r < 4; ++r)
      mc[r] = fmaxf(fmaxf(sf[0][r], sf[1][r]), fmaxf(sf[2][r], sf[3][r]));
#pragma unroll
    for (int off = 1; off < 16; off <<= 1)
#pragma unroll
      for (int r = 0; r < 4; ++r) mc[r] = fmaxf(mc[r], __shfl_xor(mc[r], off, 64));
#pragma unroll
    for (int r = 0; r < 4; ++r) {
      float mnew = fmaxf(m_i[r], mc[r]);
      float alpha = __expf(m_i[r] - mnew);
      m_i[r] = mnew;
      lp[r] *= alpha;
#pragma unroll
      for (int ot = 0; ot < 8; ++ot) of[ot][r] *= alpha;
    }
    // p values + LOCAL l partial (cross-lane sum deferred to epilogue)
#pragma unroll
    for (int ni = 0; ni < 4; ++ni)
#pragma unroll
      for (int r = 0; r < 4; ++r) {
        float p = __expf(sf[ni][r] - m_i[r]);
        sf[ni][r] = p;
        lp[r] += p;
      }
    // write P (C-layout -> LDS, rows w*16+quad*4+r), swizzled; wave-private
#pragma unroll
    for (int ni = 0; ni < 4; ++ni)
#pragma unroll
      for (int r = 0; r < 4; ++r) {
        int row = w * 16 + quad * 4 + r;
        Ps[row * 64 + ((ni * 16 + c) ^ ((row & 7) * 8))] = f2bf(sf[ni][r]);
      }
    // O += P V  (A-frag of P: rows w*16+c; B-frag of V from Vts)
    s16x8 pa[2];
    pa[0] = *(const s16x8*)(&Ps[(w * 16 + c) * 64 + ((quad * 8) ^ c7)]);
    pa[1] = *(const s16x8*)(&Ps[(w * 16 + c) * 64 + ((32 + quad * 8) ^ c7)]);
#pragma unroll
    for (int ot = 0; ot < 8; ++ot) {
#pragma unroll
      for (int kk = 0; kk < 2; ++kk) {
        s16x8 vfr = *(const s16x8*)(&Vts[cur][(ot * 16 + c) * 64 + ((kk * 32 + quad * 8) ^ c7)]);
        of[ot] = __builtin_amdgcn_mfma_f32_16x16x32_bf16(pa[kk], vfr, of[ot], 0, 0, 0);
      }
    }

    // single barrier per iteration: drains the prefetch (covered by compute)
    // and fences buf reuse across waves.
    __syncthreads();
    cur ^= 1;
  }

  // epilogue: reduce l partials across the 16 c-lanes, then O /= l, store bf16 ctx
#pragma unroll
  for (int off = 1; off < 16; off <<= 1)
#pragma unroll
    for (int r = 0; r < 4; ++r) lp[r] += __shfl_xor(lp[r], off, 64);
  float inv[4];
#pragma unroll
  for (int r = 0; r < 4; ++r) inv[r] = 1.0f / lp[r];
  u16* obase = O + ((size_t)(b * T_ + q0) * H_ + h) * HD_;
#pragma unroll
  for (int ot = 0; ot < 8; ++ot)
#pragma unroll
    for (int r = 0; r < 4; ++r)
      obase[(size_t)(w * 16 + quad * 4 + r) * KVSTRIDE_ + ot * 16 + c] = f2bf(of[ot][r] * inv[r]);
}

// ---------------- launch (4 dispatches) ----------------
extern "C" void kernel_launch(void* const* d_in, const int* in_sizes, int n_in,
                              void* d_out, int out_size, void* d_ws, size_t ws_size,
                              hipStream_t stream) {
  const float* x = (const float*)d_in[0];
  const float* Wq = (const float*)d_in[1];
  const float* Wk = (const float*)d_in[2];
  const float* Wv = (const float*)d_in[3];
  const float* Wo = (const float*)d_in[4];
  const float* qw = (const float*)d_in[5];
  const float* kw = (const float*)d_in[6];
  float* out = (float*)d_out;

  const size_t xE = (size_t)B_ * T_ * D_;   // 8388608
  const size_t wE = (size_t)D_ * H_ * HD_;  // 4194304
  const size_t ropeB = (size_t)T_ * 64 * sizeof(float2);  // 1 MB
  const size_t need = xE * 2 * 5 + wE * 2 * 4 + ropeB;  // ~113 MB
  if (ws_size < need) return;

  char* ws = (char*)d_ws;
  u16* xb = (u16*)ws;    ws += xE * 2;
  u16* wqkb = (u16*)ws;  ws += wE * 2 * 2;  // Wq || Wk adjacent
  u16* wvb = (u16*)ws;   ws += wE * 2;
  u16* wob = (u16*)ws;   ws += wE * 2;
  u16* qb = (u16*)ws;    ws += xE * 2;
  u16* kb = (u16*)ws;    ws += xE * 2;
  u16* vtb = (u16*)ws;   ws += xE * 2;   // V^T: [H*HD][B*T]
  u16* ctxb = (u16*)ws;  ws += xE * 2;
  float2* rope = (float2*)ws; ws += ropeB;

  // 1) fused casts + rope table
  cvt_all<<<25088, 256, 0, stream>>>(x, Wq, Wk, Wv, Wo, xb, wqkb, wvb, wob, rope);

  // 2) QK GEMM (+fused norm/rope, split into qb/kb) and V^T GEMM, one dispatch
  dim3 gqkv(32, 48);
  gemm_qkv<<<gqkv, 256, 0, stream>>>(xb, wqkb, wvb, qb, kb, vtb, qw, kw, rope);

  // 3) attention
  attn_fwd<<<B_ * H_ * (T_ / 64), 256, 0, stream>>>(qb, kb, vtb, ctxb);

  // 4) output projection
  dim3 gg(16, 32);
  gemm_btn<<<gg, 256, 0, stream>>>(ctxb, wob, out, 4096, 2048, 2048);
}